// Round 2
// baseline (1220.023 us; speedup 1.0000x reference)
//
#include <hip/hip_runtime.h>
#include <math.h>

#define BB 16
#define NN 4096
#define M_TOT (BB*NN)   // 65536 points

__device__ __forceinline__ float gelu_t(float x){
    float x3 = x*x*x;
    float t = tanhf(0.7978845608028654f*(x + 0.044715f*x3));
    return 0.5f*x*(1.0f+t);
}

// ---------------- conv 3x3, pad 1, stride s, GELU epilogue ----------------
__global__ void conv3x3_k(const float* __restrict__ in, const float* __restrict__ w,
                          const float* __restrict__ bias, float* __restrict__ out,
                          int Cin, int Hin, int Win, int Cout, int Hout, int Wout, int stride)
{
    int wo = blockIdx.x*16 + threadIdx.x;
    int ho = blockIdx.y*16 + threadIdx.y;
    int bc = blockIdx.z;
    int co = bc % Cout, b = bc / Cout;
    if (wo >= Wout || ho >= Hout) return;
    const float* wp = w + co*Cin*9;
    const float* ip = in + (size_t)(b*Cin)*Hin*Win;
    float acc = bias[co];
    int hbase = ho*stride - 1, wbase = wo*stride - 1;
    for (int ci = 0; ci < Cin; ++ci) {
        const float* ic = ip + (size_t)ci*Hin*Win;
        const float* wc = wp + ci*9;
        #pragma unroll
        for (int kh = 0; kh < 3; ++kh) {
            int hi = hbase + kh;
            if ((unsigned)hi >= (unsigned)Hin) continue;
            #pragma unroll
            for (int kw = 0; kw < 3; ++kw) {
                int wi = wbase + kw;
                if ((unsigned)wi >= (unsigned)Win) continue;
                acc = fmaf(ic[hi*Win + wi], wc[kh*3+kw], acc);
            }
        }
    }
    out[(((size_t)b*Cout + co)*Hout + ho)*Wout + wo] = gelu_t(acc);
}

// ---------------- global avg pool 7x7: [B,64,7,7] -> [B,64] ----------------
__global__ void avgpool7_k(const float* __restrict__ in, float* __restrict__ out){
    int i = blockIdx.x*blockDim.x + threadIdx.x;
    if (i >= BB*64) return;
    const float* p = in + (size_t)i*49;
    float s = 0.f;
    #pragma unroll
    for (int k = 0; k < 49; ++k) s += p[k];
    out[i] = s * (1.0f/49.0f);
}

// ---------------- positional embedding: points [M,2] -> pe [M,48] ----------------
__global__ void embed_k(const float* __restrict__ points, float* __restrict__ pe){
    int idx = blockIdx.x*blockDim.x + threadIdx.x;
    if (idx >= M_TOT*48) return;
    int m = idx / 48, e = idx % 48;
    int i = e >> 2, r = e & 3;
    float f = (float)(1 << i);
    float p = points[m*2 + (r & 1)];
    float s = f * p;
    pe[idx] = (r < 2) ? sinf(s) : cosf(s);
}

// ---------------- SGEMM: C[m,n] = act(sum_k A[m,k]*W[n,k] + bias[n]) ----------------
#define BM 64
#define BN 64
#define BKK 16
__global__ __launch_bounds__(256) void gemm_k(const float* __restrict__ A, int lda,
        const float* __restrict__ W, const float* __restrict__ bias,
        float* __restrict__ C, int ldc, int M, int N, int K, int act)
{
    __shared__ float As[BKK][BM];   // k-major: conflict-free b128 reads
    __shared__ float Ws[BKK][BN];
    int tid = threadIdx.x;
    int tx = tid & 15, ty = tid >> 4;
    int bm = blockIdx.x * BM;
    int bn = blockIdx.y * BN;
    int lr = tid >> 2;            // 0..63 (row within tile)
    int lc = (tid & 3) * 4;       // 0,4,8,12 (k offset)
    float acc[4][4] = {};
    for (int k0 = 0; k0 < K; k0 += BKK) {
        float4 av = *(const float4*)(A + (size_t)(bm+lr)*lda + k0 + lc);
        float4 wv = *(const float4*)(W + (size_t)(bn+lr)*K  + k0 + lc);
        As[lc+0][lr] = av.x; As[lc+1][lr] = av.y; As[lc+2][lr] = av.z; As[lc+3][lr] = av.w;
        Ws[lc+0][lr] = wv.x; Ws[lc+1][lr] = wv.y; Ws[lc+2][lr] = wv.z; Ws[lc+3][lr] = wv.w;
        __syncthreads();
        #pragma unroll
        for (int k = 0; k < BKK; ++k) {
            float4 a = *(const float4*)&As[k][ty*4];
            float4 w = *(const float4*)&Ws[k][tx*4];
            float aa[4] = {a.x,a.y,a.z,a.w};
            float ww[4] = {w.x,w.y,w.z,w.w};
            #pragma unroll
            for (int i = 0; i < 4; ++i)
                #pragma unroll
                for (int j = 0; j < 4; ++j)
                    acc[i][j] = fmaf(aa[i], ww[j], acc[i][j]);
        }
        __syncthreads();
    }
    #pragma unroll
    for (int i = 0; i < 4; ++i) {
        int m = bm + ty*4 + i;
        int n = bn + tx*4;
        float4 v;
        v.x = acc[i][0] + bias[n+0];
        v.y = acc[i][1] + bias[n+1];
        v.z = acc[i][2] + bias[n+2];
        v.w = acc[i][3] + bias[n+3];
        if (act) { v.x = gelu_t(v.x); v.y = gelu_t(v.y); v.z = gelu_t(v.z); v.w = gelu_t(v.w); }
        *(float4*)(C + (size_t)m*ldc + n) = v;
    }
}

// ---------------- head GEMM fused with final 512->1 dot ----------------
// h[m,n] = gelu(fused[m,:]@hw1[n,:] + hb1[n]); out[m] += sum_n h[m,n]*hw2[n]
__global__ __launch_bounds__(256) void gemm_head_k(const float* __restrict__ A, int lda,
        const float* __restrict__ W, const float* __restrict__ bias,
        const float* __restrict__ w2, float* __restrict__ out, int K)
{
    __shared__ float As[BKK][BM];
    __shared__ float Ws[BKK][BN];
    int tid = threadIdx.x;
    int tx = tid & 15, ty = tid >> 4;
    int bm = blockIdx.x * BM;
    int bn = blockIdx.y * BN;
    int lr = tid >> 2;
    int lc = (tid & 3) * 4;
    float acc[4][4] = {};
    for (int k0 = 0; k0 < K; k0 += BKK) {
        float4 av = *(const float4*)(A + (size_t)(bm+lr)*lda + k0 + lc);
        float4 wv = *(const float4*)(W + (size_t)(bn+lr)*K  + k0 + lc);
        As[lc+0][lr] = av.x; As[lc+1][lr] = av.y; As[lc+2][lr] = av.z; As[lc+3][lr] = av.w;
        Ws[lc+0][lr] = wv.x; Ws[lc+1][lr] = wv.y; Ws[lc+2][lr] = wv.z; Ws[lc+3][lr] = wv.w;
        __syncthreads();
        #pragma unroll
        for (int k = 0; k < BKK; ++k) {
            float4 a = *(const float4*)&As[k][ty*4];
            float4 w = *(const float4*)&Ws[k][tx*4];
            float aa[4] = {a.x,a.y,a.z,a.w};
            float ww[4] = {w.x,w.y,w.z,w.w};
            #pragma unroll
            for (int i = 0; i < 4; ++i)
                #pragma unroll
                for (int j = 0; j < 4; ++j)
                    acc[i][j] = fmaf(aa[i], ww[j], acc[i][j]);
        }
        __syncthreads();
    }
    int n = bn + tx*4;
    float4 bv = *(const float4*)(bias + n);
    float4 w2v = *(const float4*)(w2 + n);
    #pragma unroll
    for (int i = 0; i < 4; ++i) {
        float s = gelu_t(acc[i][0] + bv.x) * w2v.x
                + gelu_t(acc[i][1] + bv.y) * w2v.y
                + gelu_t(acc[i][2] + bv.z) * w2v.z
                + gelu_t(acc[i][3] + bv.w) * w2v.w;
        // reduce across the 16 tx lanes (contiguous lanes within a wave)
        #pragma unroll
        for (int off = 8; off > 0; off >>= 1) s += __shfl_down(s, off, 16);
        if (tx == 0) atomicAdd(&out[bm + ty*4 + i], s);
    }
}

// ---------------- init out with final bias ----------------
__global__ void initout_k(float* __restrict__ out, const float* __restrict__ b2){
    int i = blockIdx.x*blockDim.x + threadIdx.x;
    if (i < M_TOT) out[i] = b2[0];
}

// ---------------- bilinear patch extraction -> fused cols [256..511] ----------------
__global__ void patch_k(const float* __restrict__ fmap, const float* __restrict__ points,
                        float* __restrict__ fused)
{
    int t = blockIdx.x*blockDim.x + threadIdx.x;   // M*64 threads
    int m = t >> 6, ij = t & 63;
    if (m >= M_TOT) return;
    int i = ij >> 3, j = ij & 7;
    int b = m >> 12;
    const int W = 56, H = 56;
    float px = points[m*2], py = points[m*2+1];
    float cx = px*2.f - 1.f, cy = py*2.f - 1.f;
    const float step = 2.0f/55.0f;
    float gx = cx + ((float)i - 3.5f)*step;
    float gy = cy + ((float)j - 3.5f)*step;
    float ix = (gx + 1.f)*0.5f*55.f;
    float iy = (gy + 1.f)*0.5f*55.f;
    float x0f = floorf(ix), y0f = floorf(iy);
    int x0 = (int)x0f, y0 = (int)y0f;
    int x1 = x0 + 1,  y1 = y0 + 1;
    float wx1 = ix - x0f, wx0 = 1.f - wx1;
    float wy1 = iy - y0f, wy0 = 1.f - wy1;
    float v00 = ((x0>=0)&&(x0<W)&&(y0>=0)&&(y0<H)) ? 1.f : 0.f;
    float v10 = ((x1>=0)&&(x1<W)&&(y0>=0)&&(y0<H)) ? 1.f : 0.f;
    float v01 = ((x0>=0)&&(x0<W)&&(y1>=0)&&(y1<H)) ? 1.f : 0.f;
    float v11 = ((x1>=0)&&(x1<W)&&(y1>=0)&&(y1<H)) ? 1.f : 0.f;
    float w00 = wx0*wy0*v00, w10 = wx1*wy0*v10, w01 = wx0*wy1*v01, w11 = wx1*wy1*v11;
    int cx0 = min(max(x0,0),W-1), cx1 = min(max(x1,0),W-1);
    int cy0 = min(max(y0,0),H-1), cy1 = min(max(y1,0),H-1);
    int i00 = cy0*W + cx0, i10 = cy0*W + cx1, i01 = cy1*W + cx0, i11 = cy1*W + cx1;
    #pragma unroll
    for (int c = 0; c < 4; ++c) {
        const float* f = fmap + ((size_t)(b*4 + c))*H*W;
        float v = w00*f[i00] + w10*f[i10] + w01*f[i01] + w11*f[i11];
        fused[(size_t)m*576 + 256 + c*64 + ij] = v;
    }
}

// ---------------- broadcast gc [B,64] -> fused cols [512..575] ----------------
__global__ void gcbc_k(const float* __restrict__ gc, float* __restrict__ fused){
    int t = blockIdx.x*blockDim.x + threadIdx.x;   // M*64
    int m = t >> 6, c = t & 63;
    if (m >= M_TOT) return;
    int b = m >> 12;
    fused[(size_t)m*576 + 512 + c] = gc[b*64 + c];
}

extern "C" void kernel_launch(void* const* d_in, const int* in_sizes, int n_in,
                              void* d_out, int out_size, void* d_ws, size_t ws_size,
                              hipStream_t stream) {
    const float* points = (const float*)d_in[0];
    const float* images = (const float*)d_in[1];
    const float* pw1 = (const float*)d_in[2];  const float* pb1 = (const float*)d_in[3];
    const float* pw2 = (const float*)d_in[4];  const float* pb2 = (const float*)d_in[5];
    const float* pw3 = (const float*)d_in[6];  const float* pb3 = (const float*)d_in[7];
    const float* gw1 = (const float*)d_in[8];  const float* gb1 = (const float*)d_in[9];
    const float* gw2 = (const float*)d_in[10]; const float* gb2 = (const float*)d_in[11];
    const float* gw3 = (const float*)d_in[12]; const float* gb3 = (const float*)d_in[13];
    const float* gw4 = (const float*)d_in[14]; const float* gb4 = (const float*)d_in[15];
    const float* gw5 = (const float*)d_in[16]; const float* gb5 = (const float*)d_in[17];
    const float* lw1 = (const float*)d_in[18]; const float* lb1 = (const float*)d_in[19];
    const float* lw2 = (const float*)d_in[20]; const float* lb2 = (const float*)d_in[21];
    const float* hw1 = (const float*)d_in[22]; const float* hb1 = (const float*)d_in[23];
    const float* hw2 = (const float*)d_in[24]; const float* hb2 = (const float*)d_in[25];
    float* out = (float*)d_out;

    // ---- workspace layout (lifetime-aliased; peak ~219 MB) ----
    // [fused: M*576][hid: M*256][fmap: 16*4*56*56][gc: 1024]
    // pe (M*48) and all conv temps alias INSIDE the fused region: they are
    // dead before gemm2 writes fused (single-stream serialization).
    float* ws    = (float*)d_ws;
    float* fused = ws;                                   // 37,748,736 floats
    float* hid   = fused + (size_t)M_TOT*576;            // 16,777,216
    float* fmap  = hid   + (size_t)M_TOT*256;            // 200,704
    float* gc    = fmap  + (size_t)16*4*56*56;           // 1,024

    float* pe = fused;                                   // M*48 = 3,145,728
    float* ct = fused + (size_t)M_TOT*48;                // conv temps, ~6.5M floats
    float* f1 = ct;                                      // 16*16*112*112 = 3,211,264
    float* f2 = f1 + (size_t)16*16*112*112;              // 16*32*56*56  = 1,605,632
    float* g1 = f2 + (size_t)16*32*56*56;                // 16*4*112*112 =   802,816
    float* g2 = g1 + (size_t)16*4*112*112;               // 16*8*56*56   =   401,408
    float* g3 = g2 + (size_t)16*8*56*56;                 // 16*16*28*28  =   200,704
    float* g4 = g3 + (size_t)16*16*28*28;                // 16*32*14*14  =   100,352
    float* g5 = g4 + (size_t)16*32*14*14;                // 16*64*7*7    =    50,176

    dim3 blk(16,16);
    // plane encoder
    conv3x3_k<<<dim3(7,7,16*16),  blk, 0, stream>>>(images, pw1, pb1, f1,   3, 224,224, 16, 112,112, 2);
    conv3x3_k<<<dim3(4,4,16*32),  blk, 0, stream>>>(f1,     pw2, pb2, f2,  16, 112,112, 32,  56, 56, 2);
    conv3x3_k<<<dim3(4,4,16*4),   blk, 0, stream>>>(f2,     pw3, pb3, fmap,32,  56, 56,  4,  56, 56, 1);
    // global encoder
    conv3x3_k<<<dim3(7,7,16*4),   blk, 0, stream>>>(images, gw1, gb1, g1,   3, 224,224,  4, 112,112, 2);
    conv3x3_k<<<dim3(4,4,16*8),   blk, 0, stream>>>(g1,     gw2, gb2, g2,   4, 112,112,  8,  56, 56, 2);
    conv3x3_k<<<dim3(2,2,16*16),  blk, 0, stream>>>(g2,     gw3, gb3, g3,   8,  56, 56, 16,  28, 28, 2);
    conv3x3_k<<<dim3(1,1,16*32),  blk, 0, stream>>>(g3,     gw4, gb4, g4,  16,  28, 28, 32,  14, 14, 2);
    conv3x3_k<<<dim3(1,1,16*64),  blk, 0, stream>>>(g4,     gw5, gb5, g5,  32,  14, 14, 64,   7,  7, 2);
    avgpool7_k<<<4, 256, 0, stream>>>(g5, gc);
    // point branch
    embed_k<<<(M_TOT*48)/256, 256, 0, stream>>>(points, pe);
    gemm_k<<<dim3(M_TOT/BM, 256/BN), 256, 0, stream>>>(pe,  48,  lw1, lb1, hid,   256, M_TOT, 256,  48, 1);
    gemm_k<<<dim3(M_TOT/BM, 256/BN), 256, 0, stream>>>(hid, 256, lw2, lb2, fused, 576, M_TOT, 256, 256, 0);
    // patches + global broadcast into fused
    patch_k<<<(M_TOT*64)/256, 256, 0, stream>>>(fmap, points, fused);
    gcbc_k<<<(M_TOT*64)/256, 256, 0, stream>>>(gc, fused);
    // head: gemm(576->512) + gelu + dot(512->1), fused via atomics
    initout_k<<<M_TOT/256, 256, 0, stream>>>(out, hb2);
    gemm_head_k<<<dim3(M_TOT/BM, 512/BN), 256, 0, stream>>>(fused, 576, hw1, hb1, hw2, out, 576);
}

// Round 3
// 688.702 us; speedup vs baseline: 1.7715x; 1.7715x over previous
//
#include <hip/hip_runtime.h>
#include <math.h>

#define BB 16
#define NN 4096
#define M_TOT (BB*NN)   // 65536 points

typedef __attribute__((ext_vector_type(8))) short s8v;   // 8 bf16 = 4 VGPRs
typedef __attribute__((ext_vector_type(4))) float f4v;

__device__ __forceinline__ float gelu_t(float x){
    float x3 = x*x*x;
    float t = tanhf(0.7978845608028654f*(x + 0.044715f*x3));
    return 0.5f*x*(1.0f+t);
}

// round-to-nearest-even fp32 -> bf16 (as ushort)
__device__ __forceinline__ unsigned short f2bf(float f){
    unsigned int u = __float_as_uint(f);
    u += 0x7fffu + ((u >> 16) & 1u);
    return (unsigned short)(u >> 16);
}

// ---------------- conv 3x3, pad 1, stride s, GELU epilogue ----------------
__global__ void conv3x3_k(const float* __restrict__ in, const float* __restrict__ w,
                          const float* __restrict__ bias, float* __restrict__ out,
                          int Cin, int Hin, int Win, int Cout, int Hout, int Wout, int stride)
{
    int wo = blockIdx.x*16 + threadIdx.x;
    int ho = blockIdx.y*16 + threadIdx.y;
    int bc = blockIdx.z;
    int co = bc % Cout, b = bc / Cout;
    if (wo >= Wout || ho >= Hout) return;
    const float* wp = w + co*Cin*9;
    const float* ip = in + (size_t)(b*Cin)*Hin*Win;
    float acc = bias[co];
    int hbase = ho*stride - 1, wbase = wo*stride - 1;
    for (int ci = 0; ci < Cin; ++ci) {
        const float* ic = ip + (size_t)ci*Hin*Win;
        const float* wc = wp + ci*9;
        #pragma unroll
        for (int kh = 0; kh < 3; ++kh) {
            int hi = hbase + kh;
            if ((unsigned)hi >= (unsigned)Hin) continue;
            #pragma unroll
            for (int kw = 0; kw < 3; ++kw) {
                int wi = wbase + kw;
                if ((unsigned)wi >= (unsigned)Win) continue;
                acc = fmaf(ic[hi*Win + wi], wc[kh*3+kw], acc);
            }
        }
    }
    out[(((size_t)b*Cout + co)*Hout + ho)*Wout + wo] = gelu_t(acc);
}

// ---------------- global avg pool 7x7: [B,64,7,7] -> [B,64] ----------------
__global__ void avgpool7_k(const float* __restrict__ in, float* __restrict__ out){
    int i = blockIdx.x*blockDim.x + threadIdx.x;
    if (i >= BB*64) return;
    const float* p = in + (size_t)i*49;
    float s = 0.f;
    #pragma unroll
    for (int k = 0; k < 49; ++k) s += p[k];
    out[i] = s * (1.0f/49.0f);
}

// ---------------- embedding: points [M,2] -> pe bf16 [M,64] (cols 48..63 = 0) ----------------
__global__ void embed_k(const float* __restrict__ points, unsigned short* __restrict__ pe){
    int idx = blockIdx.x*blockDim.x + threadIdx.x;
    if (idx >= M_TOT*64) return;
    int m = idx >> 6, e = idx & 63;
    if (e >= 48) { pe[idx] = 0; return; }
    int i = e >> 2, r = e & 3;
    float f = (float)(1 << i);
    float p = points[m*2 + (r & 1)];
    float s = f * p;
    pe[idx] = f2bf((r < 2) ? sinf(s) : cosf(s));
}

// ---------------- weight conversions ----------------
__global__ void cvt_bf16_k(const float* __restrict__ in, unsigned short* __restrict__ out, int n){
    int i = blockIdx.x*blockDim.x + threadIdx.x;
    if (i < n) out[i] = f2bf(in[i]);
}
__global__ void cvt_pad_lw1_k(const float* __restrict__ in, unsigned short* __restrict__ out){
    int i = blockIdx.x*blockDim.x + threadIdx.x;   // 256*64
    if (i >= 256*64) return;
    int r = i >> 6, c = i & 63;
    out[i] = (c < 48) ? f2bf(in[r*48 + c]) : 0;
}

// ---------------- bf16 MFMA GEMM: C[m,n] = act(sum_k A[m,k]*W[n,k] + bias[n]) ----------------
// A [M][lda] bf16, W [N][ldw] bf16 (ldw=K), C [M][ldc] bf16. 128x128 tile, BK=32, 4 waves.
#define TBM 128
#define TBN 128
#define TBK 32

#define STAGE_TILE(DST, SRC, LD) \
    { \
        _Pragma("unroll") \
        for (int r = 0; r < 2; ++r) { \
            int fi = (r*4 + wv)*64 + lane; \
            int row = fi >> 2, seg = fi & 3; \
            const unsigned short* ga = (SRC) + (size_t)row*(LD) + k0 + seg*8; \
            __builtin_amdgcn_global_load_lds( \
                (const __attribute__((address_space(1))) void*)ga, \
                (__attribute__((address_space(3))) void*)(&DST[0][0] + (r*4 + wv)*512), \
                16, 0, 0); \
        } \
    }

__global__ __launch_bounds__(256) void gemm_bf16_k(
    const unsigned short* __restrict__ A, int lda,
    const unsigned short* __restrict__ W, int ldw,
    const float* __restrict__ bias,
    unsigned short* __restrict__ C, int ldc, int K, int act)
{
    __shared__ unsigned short As[TBM][TBK];
    __shared__ unsigned short Bs[TBN][TBK];
    int tid = threadIdx.x;
    int wv = tid >> 6, lane = tid & 63;
    int q = lane >> 4, lr = lane & 15;
    int mq = (wv >> 1) * 64, nq = (wv & 1) * 64;
    const unsigned short* Ab = A + (size_t)blockIdx.x * TBM * lda;
    const unsigned short* Wb = W + (size_t)blockIdx.y * TBN * ldw;
    f4v acc[4][4];
    #pragma unroll
    for (int i = 0; i < 4; ++i)
        #pragma unroll
        for (int j = 0; j < 4; ++j) acc[i][j] = (f4v){0.f,0.f,0.f,0.f};

    for (int k0 = 0; k0 < K; k0 += TBK) {
        STAGE_TILE(As, Ab, lda)
        STAGE_TILE(Bs, Wb, ldw)
        __syncthreads();
        s8v a[4], b[4];
        #pragma unroll
        for (int t = 0; t < 4; ++t) {
            a[t] = *(const s8v*)&As[mq + t*16 + lr][q*8];
            b[t] = *(const s8v*)&Bs[nq + t*16 + lr][q*8];
        }
        #pragma unroll
        for (int mt = 0; mt < 4; ++mt)
            #pragma unroll
            for (int nt = 0; nt < 4; ++nt)
                acc[mt][nt] = __builtin_amdgcn_mfma_f32_16x16x32_bf16(a[mt], b[nt], acc[mt][nt], 0, 0, 0);
        __syncthreads();
    }
    // epilogue: bias (+gelu) -> bf16 store
    #pragma unroll
    for (int mt = 0; mt < 4; ++mt)
        #pragma unroll
        for (int r4 = 0; r4 < 4; ++r4) {
            size_t m = (size_t)blockIdx.x*TBM + mq + mt*16 + q*4 + r4;
            #pragma unroll
            for (int nt = 0; nt < 4; ++nt) {
                int n = blockIdx.y*TBN + nq + nt*16 + lr;
                float v = acc[mt][nt][r4] + bias[n];
                if (act) v = gelu_t(v);
                C[m*ldc + n] = f2bf(v);
            }
        }
}

// ---------------- head: gemm(576->512)+gelu fused with dot(512->1) ----------------
__global__ __launch_bounds__(256) void gemm_head_k(
    const unsigned short* __restrict__ A, int lda,
    const unsigned short* __restrict__ W, int ldw,
    const float* __restrict__ bias, const float* __restrict__ w2,
    float* __restrict__ out, int K)
{
    __shared__ unsigned short As[TBM][TBK];
    __shared__ unsigned short Bs[TBN][TBK];
    int tid = threadIdx.x;
    int wv = tid >> 6, lane = tid & 63;
    int q = lane >> 4, lr = lane & 15;
    int mq = (wv >> 1) * 64, nq = (wv & 1) * 64;
    const unsigned short* Ab = A + (size_t)blockIdx.x * TBM * lda;
    const unsigned short* Wb = W + (size_t)blockIdx.y * TBN * ldw;
    f4v acc[4][4];
    #pragma unroll
    for (int i = 0; i < 4; ++i)
        #pragma unroll
        for (int j = 0; j < 4; ++j) acc[i][j] = (f4v){0.f,0.f,0.f,0.f};

    for (int k0 = 0; k0 < K; k0 += TBK) {
        STAGE_TILE(As, Ab, lda)
        STAGE_TILE(Bs, Wb, ldw)
        __syncthreads();
        s8v a[4], b[4];
        #pragma unroll
        for (int t = 0; t < 4; ++t) {
            a[t] = *(const s8v*)&As[mq + t*16 + lr][q*8];
            b[t] = *(const s8v*)&Bs[nq + t*16 + lr][q*8];
        }
        #pragma unroll
        for (int mt = 0; mt < 4; ++mt)
            #pragma unroll
            for (int nt = 0; nt < 4; ++nt)
                acc[mt][nt] = __builtin_amdgcn_mfma_f32_16x16x32_bf16(a[mt], b[nt], acc[mt][nt], 0, 0, 0);
        __syncthreads();
    }
    // epilogue: gelu(acc + b1[n]) * w2[n], reduce over n, atomic into out[m]
    float bv[4], wv2[4];
    #pragma unroll
    for (int nt = 0; nt < 4; ++nt) {
        int n = blockIdx.y*TBN + nq + nt*16 + lr;
        bv[nt] = bias[n];
        wv2[nt] = w2[n];
    }
    #pragma unroll
    for (int mt = 0; mt < 4; ++mt)
        #pragma unroll
        for (int r4 = 0; r4 < 4; ++r4) {
            size_t m = (size_t)blockIdx.x*TBM + mq + mt*16 + q*4 + r4;
            float s = 0.f;
            #pragma unroll
            for (int nt = 0; nt < 4; ++nt)
                s += gelu_t(acc[mt][nt][r4] + bv[nt]) * wv2[nt];
            #pragma unroll
            for (int off = 8; off > 0; off >>= 1) s += __shfl_down(s, off, 16);
            if (lr == 0) atomicAdd(&out[m], s);
        }
}

// ---------------- init out with final bias ----------------
__global__ void initout_k(float* __restrict__ out, const float* __restrict__ b2){
    int i = blockIdx.x*blockDim.x + threadIdx.x;
    if (i < M_TOT) out[i] = b2[0];
}

// ---------------- bilinear patch extraction -> fused cols [256..511] (bf16) ----------------
__global__ void patch_k(const float* __restrict__ fmap, const float* __restrict__ points,
                        unsigned short* __restrict__ fused)
{
    int t = blockIdx.x*blockDim.x + threadIdx.x;   // M*64 threads
    int m = t >> 6, ij = t & 63;
    if (m >= M_TOT) return;
    int i = ij >> 3, j = ij & 7;
    int b = m >> 12;
    const int W = 56, H = 56;
    float px = points[m*2], py = points[m*2+1];
    float cx = px*2.f - 1.f, cy = py*2.f - 1.f;
    const float step = 2.0f/55.0f;
    float gx = cx + ((float)i - 3.5f)*step;
    float gy = cy + ((float)j - 3.5f)*step;
    float ix = (gx + 1.f)*0.5f*55.f;
    float iy = (gy + 1.f)*0.5f*55.f;
    float x0f = floorf(ix), y0f = floorf(iy);
    int x0 = (int)x0f, y0 = (int)y0f;
    int x1 = x0 + 1,  y1 = y0 + 1;
    float wx1 = ix - x0f, wx0 = 1.f - wx1;
    float wy1 = iy - y0f, wy0 = 1.f - wy1;
    float v00 = ((x0>=0)&&(x0<W)&&(y0>=0)&&(y0<H)) ? 1.f : 0.f;
    float v10 = ((x1>=0)&&(x1<W)&&(y0>=0)&&(y0<H)) ? 1.f : 0.f;
    float v01 = ((x0>=0)&&(x0<W)&&(y1>=0)&&(y1<H)) ? 1.f : 0.f;
    float v11 = ((x1>=0)&&(x1<W)&&(y1>=0)&&(y1<H)) ? 1.f : 0.f;
    float w00 = wx0*wy0*v00, w10 = wx1*wy0*v10, w01 = wx0*wy1*v01, w11 = wx1*wy1*v11;
    int cx0 = min(max(x0,0),W-1), cx1 = min(max(x1,0),W-1);
    int cy0 = min(max(y0,0),H-1), cy1 = min(max(y1,0),H-1);
    int i00 = cy0*W + cx0, i10 = cy0*W + cx1, i01 = cy1*W + cx0, i11 = cy1*W + cx1;
    #pragma unroll
    for (int c = 0; c < 4; ++c) {
        const float* f = fmap + ((size_t)(b*4 + c))*H*W;
        float v = w00*f[i00] + w10*f[i10] + w01*f[i01] + w11*f[i11];
        fused[(size_t)m*576 + 256 + c*64 + ij] = f2bf(v);
    }
}

// ---------------- broadcast gc [B,64] -> fused cols [512..575] (bf16) ----------------
__global__ void gcbc_k(const float* __restrict__ gc, unsigned short* __restrict__ fused){
    int t = blockIdx.x*blockDim.x + threadIdx.x;   // M*64
    int m = t >> 6, c = t & 63;
    if (m >= M_TOT) return;
    int b = m >> 12;
    fused[(size_t)m*576 + 512 + c] = f2bf(gc[b*64 + c]);
}

extern "C" void kernel_launch(void* const* d_in, const int* in_sizes, int n_in,
                              void* d_out, int out_size, void* d_ws, size_t ws_size,
                              hipStream_t stream) {
    const float* points = (const float*)d_in[0];
    const float* images = (const float*)d_in[1];
    const float* pw1 = (const float*)d_in[2];  const float* pb1 = (const float*)d_in[3];
    const float* pw2 = (const float*)d_in[4];  const float* pb2 = (const float*)d_in[5];
    const float* pw3 = (const float*)d_in[6];  const float* pb3 = (const float*)d_in[7];
    const float* gw1 = (const float*)d_in[8];  const float* gb1 = (const float*)d_in[9];
    const float* gw2 = (const float*)d_in[10]; const float* gb2 = (const float*)d_in[11];
    const float* gw3 = (const float*)d_in[12]; const float* gb3 = (const float*)d_in[13];
    const float* gw4 = (const float*)d_in[14]; const float* gb4 = (const float*)d_in[15];
    const float* gw5 = (const float*)d_in[16]; const float* gb5 = (const float*)d_in[17];
    const float* lw1 = (const float*)d_in[18]; const float* lb1 = (const float*)d_in[19];
    const float* lw2 = (const float*)d_in[20]; const float* lb2 = (const float*)d_in[21];
    const float* hw1 = (const float*)d_in[22]; const float* hb1 = (const float*)d_in[23];
    const float* hw2 = (const float*)d_in[24]; const float* hb2 = (const float*)d_in[25];
    float* out = (float*)d_out;

    // ---- workspace layout (~111 MB) ----
    char* base = (char*)d_ws;
    unsigned short* fused_b = (unsigned short*)base;                       // M*576 bf16
    unsigned short* hid_b   = fused_b + (size_t)M_TOT*576;                 // M*256 bf16
    float* fmap = (float*)(hid_b + (size_t)M_TOT*256);                     // 16*4*56*56
    float* gc   = fmap + (size_t)16*4*56*56;                               // 1024
    unsigned short* blw1 = (unsigned short*)(gc + 1024);                   // 256*64
    unsigned short* blw2 = blw1 + 256*64;                                  // 256*256
    unsigned short* bhw1 = blw2 + 256*256;                                 // 512*576
    // aliases inside fused region (dead before gemm2 writes fused):
    unsigned short* pe_b = fused_b;                                        // M*64 bf16
    float* ct = (float*)(base + (size_t)M_TOT*64*2);                       // conv temps
    float* f1 = ct;                                                        // 3,211,264
    float* f2 = f1 + (size_t)16*16*112*112;                                // 1,605,632
    float* g1 = f2 + (size_t)16*32*56*56;                                  //   802,816
    float* g2 = g1 + (size_t)16*4*112*112;                                 //   401,408
    float* g3 = g2 + (size_t)16*8*56*56;                                   //   200,704
    float* g4 = g3 + (size_t)16*16*28*28;                                  //   100,352
    float* g5 = g4 + (size_t)16*32*14*14;                                  //    50,176

    dim3 blk(16,16);
    // weight conversions (tiny)
    cvt_pad_lw1_k<<<64, 256, 0, stream>>>(lw1, blw1);
    cvt_bf16_k<<<256, 256, 0, stream>>>(lw2, blw2, 256*256);
    cvt_bf16_k<<<1152, 256, 0, stream>>>(hw1, bhw1, 512*576);
    // plane encoder
    conv3x3_k<<<dim3(7,7,16*16),  blk, 0, stream>>>(images, pw1, pb1, f1,   3, 224,224, 16, 112,112, 2);
    conv3x3_k<<<dim3(4,4,16*32),  blk, 0, stream>>>(f1,     pw2, pb2, f2,  16, 112,112, 32,  56, 56, 2);
    conv3x3_k<<<dim3(4,4,16*4),   blk, 0, stream>>>(f2,     pw3, pb3, fmap,32,  56, 56,  4,  56, 56, 1);
    // global encoder
    conv3x3_k<<<dim3(7,7,16*4),   blk, 0, stream>>>(images, gw1, gb1, g1,   3, 224,224,  4, 112,112, 2);
    conv3x3_k<<<dim3(4,4,16*8),   blk, 0, stream>>>(g1,     gw2, gb2, g2,   4, 112,112,  8,  56, 56, 2);
    conv3x3_k<<<dim3(2,2,16*16),  blk, 0, stream>>>(g2,     gw3, gb3, g3,   8,  56, 56, 16,  28, 28, 2);
    conv3x3_k<<<dim3(1,1,16*32),  blk, 0, stream>>>(g3,     gw4, gb4, g4,  16,  28, 28, 32,  14, 14, 2);
    conv3x3_k<<<dim3(1,1,16*64),  blk, 0, stream>>>(g4,     gw5, gb5, g5,  32,  14, 14, 64,   7,  7, 2);
    avgpool7_k<<<4, 256, 0, stream>>>(g5, gc);
    // point branch (bf16 MFMA)
    embed_k<<<(M_TOT*64)/256, 256, 0, stream>>>(points, pe_b);
    gemm_bf16_k<<<dim3(M_TOT/TBM, 256/TBN), 256, 0, stream>>>(pe_b,  64,  blw1, 64,  lb1, hid_b,   256, 64,  1);
    gemm_bf16_k<<<dim3(M_TOT/TBM, 256/TBN), 256, 0, stream>>>(hid_b, 256, blw2, 256, lb2, fused_b, 576, 256, 0);
    // patches + global broadcast into fused (bf16)
    patch_k<<<(M_TOT*64)/256, 256, 0, stream>>>(fmap, points, fused_b);
    gcbc_k<<<(M_TOT*64)/256, 256, 0, stream>>>(gc, fused_b);
    // head: MFMA gemm(576->512)+gelu+dot(512->1) fused via atomics
    initout_k<<<M_TOT/256, 256, 0, stream>>>(out, hb2);
    gemm_head_k<<<dim3(M_TOT/TBM, 512/TBN), 256, 0, stream>>>(fused_b, 576, bhw1, 576, hb1, hw2, out, 576);
}

// Round 4
// 545.990 us; speedup vs baseline: 2.2345x; 1.2614x over previous
//
#include <hip/hip_runtime.h>
#include <math.h>

#define BB 16
#define NN 4096
#define M_TOT (BB*NN)   // 65536 points

typedef __attribute__((ext_vector_type(8))) short s8v;   // 8 bf16 = 4 VGPRs
typedef __attribute__((ext_vector_type(4))) float f4v;

__device__ __forceinline__ float gelu_t(float x){
    float x3 = x*x*x;
    float t = tanhf(0.7978845608028654f*(x + 0.044715f*x3));
    return 0.5f*x*(1.0f+t);
}

__device__ __forceinline__ unsigned short f2bf(float f){
    unsigned int u = __float_as_uint(f);
    u += 0x7fffu + ((u >> 16) & 1u);
    return (unsigned short)(u >> 16);
}

// ---------------- LDS-tiled conv 3x3, pad 1, GELU epilogue ----------------
// Block: 256 threads = 16x16 output tile, computes ALL COUT channels.
// Per ci: stage input tile to LDS once, 9 LDS reads/thread, COUT*9 FMAs with
// scalar (wave-uniform) weights. Grid: (tilesX, tilesY, B).
template<int CIN, int COUT, int STRIDE>
__global__ __launch_bounds__(256) void conv_tile_k(
    const float* __restrict__ in, const float* __restrict__ w,
    const float* __restrict__ bias, float* __restrict__ out,
    int Hin, int Win, int Hout, int Wout)
{
    constexpr int IW = 15*STRIDE + 3;          // input tile span (18 or 33)
    constexpr int IH = IW;
    __shared__ float tile[IH][IW + 1];
    int tid = threadIdx.x;
    int tx = tid & 15, ty = tid >> 4;
    int b = blockIdx.z;
    int wo = blockIdx.x*16 + tx;
    int ho = blockIdx.y*16 + ty;
    int win0 = blockIdx.x*16*STRIDE - 1;
    int hin0 = blockIdx.y*16*STRIDE - 1;
    bool valid = (wo < Wout) && (ho < Hout);

    float acc[COUT];
    #pragma unroll
    for (int co = 0; co < COUT; ++co) acc[co] = bias[co];

    const float* ib = in + (size_t)(b*CIN)*Hin*Win;
    for (int ci = 0; ci < CIN; ++ci) {
        __syncthreads();
        const float* ic = ib + (size_t)ci*Hin*Win;
        for (int idx = tid; idx < IH*IW; idx += 256) {
            int r = idx / IW, c = idx - r*IW;
            int hi = hin0 + r, wi = win0 + c;
            float v = 0.f;
            if ((unsigned)hi < (unsigned)Hin && (unsigned)wi < (unsigned)Win)
                v = ic[hi*Win + wi];
            tile[r][c] = v;
        }
        __syncthreads();
        float vv[9];
        #pragma unroll
        for (int kh = 0; kh < 3; ++kh)
            #pragma unroll
            for (int kw = 0; kw < 3; ++kw)
                vv[kh*3+kw] = tile[ty*STRIDE + kh][tx*STRIDE + kw];
        const float* wc = w + ci*9;
        #pragma unroll
        for (int co = 0; co < COUT; ++co) {
            const float* wp = wc + co*CIN*9;
            #pragma unroll
            for (int k = 0; k < 9; ++k)
                acc[co] = fmaf(vv[k], wp[k], acc[co]);
        }
    }
    if (valid) {
        size_t obase = ((size_t)b*COUT)*Hout*Wout + (size_t)ho*Wout + wo;
        #pragma unroll
        for (int co = 0; co < COUT; ++co)
            out[obase + (size_t)co*Hout*Wout] = gelu_t(acc[co]);
    }
}

// ---------------- fallback scalar conv (tiny tail maps) ----------------
__global__ void conv3x3_k(const float* __restrict__ in, const float* __restrict__ w,
                          const float* __restrict__ bias, float* __restrict__ out,
                          int Cin, int Hin, int Win, int Cout, int Hout, int Wout, int stride)
{
    int wo = blockIdx.x*16 + threadIdx.x;
    int ho = blockIdx.y*16 + threadIdx.y;
    int bc = blockIdx.z;
    int co = bc % Cout, b = bc / Cout;
    if (wo >= Wout || ho >= Hout) return;
    const float* wp = w + co*Cin*9;
    const float* ip = in + (size_t)(b*Cin)*Hin*Win;
    float acc = bias[co];
    int hbase = ho*stride - 1, wbase = wo*stride - 1;
    for (int ci = 0; ci < Cin; ++ci) {
        const float* ic = ip + (size_t)ci*Hin*Win;
        const float* wc = wp + ci*9;
        #pragma unroll
        for (int kh = 0; kh < 3; ++kh) {
            int hi = hbase + kh;
            if ((unsigned)hi >= (unsigned)Hin) continue;
            #pragma unroll
            for (int kw = 0; kw < 3; ++kw) {
                int wi = wbase + kw;
                if ((unsigned)wi >= (unsigned)Win) continue;
                acc = fmaf(ic[hi*Win + wi], wc[kh*3+kw], acc);
            }
        }
    }
    out[(((size_t)b*Cout + co)*Hout + ho)*Wout + wo] = gelu_t(acc);
}

// ---------------- global avg pool 7x7: [B,64,7,7] -> [B,64] ----------------
__global__ void avgpool7_k(const float* __restrict__ in, float* __restrict__ out){
    int i = blockIdx.x*blockDim.x + threadIdx.x;
    if (i >= BB*64) return;
    const float* p = in + (size_t)i*49;
    float s = 0.f;
    #pragma unroll
    for (int k = 0; k < 49; ++k) s += p[k];
    out[i] = s * (1.0f/49.0f);
}

// ---------------- embedding: points [M,2] -> pe bf16 [M,64] (cols 48..63 = 0) ----------------
__global__ void embed_k(const float* __restrict__ points, unsigned short* __restrict__ pe){
    int idx = blockIdx.x*blockDim.x + threadIdx.x;
    if (idx >= M_TOT*64) return;
    int m = idx >> 6, e = idx & 63;
    if (e >= 48) { pe[idx] = 0; return; }
    int i = e >> 2, r = e & 3;
    float f = (float)(1 << i);
    float p = points[m*2 + (r & 1)];
    float s = f * p;
    pe[idx] = f2bf((r < 2) ? sinf(s) : cosf(s));
}

// ---------------- weight conversions ----------------
__global__ void cvt_bf16_k(const float* __restrict__ in, unsigned short* __restrict__ out, int n){
    int i = blockIdx.x*blockDim.x + threadIdx.x;
    if (i < n) out[i] = f2bf(in[i]);
}
__global__ void cvt_pad_lw1_k(const float* __restrict__ in, unsigned short* __restrict__ out){
    int i = blockIdx.x*blockDim.x + threadIdx.x;   // 256*64
    if (i >= 256*64) return;
    int r = i >> 6, c = i & 63;
    out[i] = (c < 48) ? f2bf(in[r*48 + c]) : 0;
}

// ---------------- bf16 MFMA GEMM: C[m,n] = act(sum_k A[m,k]*W[n,k] + bias[n]) ----------------
#define TBM 128
#define TBN 128
#define TBK 32

#define STAGE_TILE(DST, SRC, LD) \
    { \
        _Pragma("unroll") \
        for (int r = 0; r < 2; ++r) { \
            int fi = (r*4 + wv)*64 + lane; \
            int row = fi >> 2, seg = fi & 3; \
            const unsigned short* ga = (SRC) + (size_t)row*(LD) + k0 + seg*8; \
            __builtin_amdgcn_global_load_lds( \
                (const __attribute__((address_space(1))) void*)ga, \
                (__attribute__((address_space(3))) void*)(&DST[0][0] + (r*4 + wv)*512), \
                16, 0, 0); \
        } \
    }

__global__ __launch_bounds__(256) void gemm_bf16_k(
    const unsigned short* __restrict__ A, int lda,
    const unsigned short* __restrict__ W, int ldw,
    const float* __restrict__ bias,
    unsigned short* __restrict__ C, int ldc, int K, int act)
{
    __shared__ unsigned short As[TBM][TBK];
    __shared__ unsigned short Bs[TBN][TBK];
    int tid = threadIdx.x;
    int wv = tid >> 6, lane = tid & 63;
    int q = lane >> 4, lr = lane & 15;
    int mq = (wv >> 1) * 64, nq = (wv & 1) * 64;
    const unsigned short* Ab = A + (size_t)blockIdx.x * TBM * lda;
    const unsigned short* Wb = W + (size_t)blockIdx.y * TBN * ldw;
    f4v acc[4][4];
    #pragma unroll
    for (int i = 0; i < 4; ++i)
        #pragma unroll
        for (int j = 0; j < 4; ++j) acc[i][j] = (f4v){0.f,0.f,0.f,0.f};

    for (int k0 = 0; k0 < K; k0 += TBK) {
        STAGE_TILE(As, Ab, lda)
        STAGE_TILE(Bs, Wb, ldw)
        __syncthreads();
        s8v a[4], b[4];
        #pragma unroll
        for (int t = 0; t < 4; ++t) {
            a[t] = *(const s8v*)&As[mq + t*16 + lr][q*8];
            b[t] = *(const s8v*)&Bs[nq + t*16 + lr][q*8];
        }
        #pragma unroll
        for (int mt = 0; mt < 4; ++mt)
            #pragma unroll
            for (int nt = 0; nt < 4; ++nt)
                acc[mt][nt] = __builtin_amdgcn_mfma_f32_16x16x32_bf16(a[mt], b[nt], acc[mt][nt], 0, 0, 0);
        __syncthreads();
    }
    #pragma unroll
    for (int mt = 0; mt < 4; ++mt)
        #pragma unroll
        for (int r4 = 0; r4 < 4; ++r4) {
            size_t m = (size_t)blockIdx.x*TBM + mq + mt*16 + q*4 + r4;
            #pragma unroll
            for (int nt = 0; nt < 4; ++nt) {
                int n = blockIdx.y*TBN + nq + nt*16 + lr;
                float v = acc[mt][nt][r4] + bias[n];
                if (act) v = gelu_t(v);
                C[m*ldc + n] = f2bf(v);
            }
        }
}

// ---------------- head: gemm(576->512)+gelu fused with dot(512->1) ----------------
__global__ __launch_bounds__(256) void gemm_head_k(
    const unsigned short* __restrict__ A, int lda,
    const unsigned short* __restrict__ W, int ldw,
    const float* __restrict__ bias, const float* __restrict__ w2,
    float* __restrict__ out, int K)
{
    __shared__ unsigned short As[TBM][TBK];
    __shared__ unsigned short Bs[TBN][TBK];
    int tid = threadIdx.x;
    int wv = tid >> 6, lane = tid & 63;
    int q = lane >> 4, lr = lane & 15;
    int mq = (wv >> 1) * 64, nq = (wv & 1) * 64;
    const unsigned short* Ab = A + (size_t)blockIdx.x * TBM * lda;
    const unsigned short* Wb = W + (size_t)blockIdx.y * TBN * ldw;
    f4v acc[4][4];
    #pragma unroll
    for (int i = 0; i < 4; ++i)
        #pragma unroll
        for (int j = 0; j < 4; ++j) acc[i][j] = (f4v){0.f,0.f,0.f,0.f};

    for (int k0 = 0; k0 < K; k0 += TBK) {
        STAGE_TILE(As, Ab, lda)
        STAGE_TILE(Bs, Wb, ldw)
        __syncthreads();
        s8v a[4], b[4];
        #pragma unroll
        for (int t = 0; t < 4; ++t) {
            a[t] = *(const s8v*)&As[mq + t*16 + lr][q*8];
            b[t] = *(const s8v*)&Bs[nq + t*16 + lr][q*8];
        }
        #pragma unroll
        for (int mt = 0; mt < 4; ++mt)
            #pragma unroll
            for (int nt = 0; nt < 4; ++nt)
                acc[mt][nt] = __builtin_amdgcn_mfma_f32_16x16x32_bf16(a[mt], b[nt], acc[mt][nt], 0, 0, 0);
        __syncthreads();
    }
    float bv[4], wv2[4];
    #pragma unroll
    for (int nt = 0; nt < 4; ++nt) {
        int n = blockIdx.y*TBN + nq + nt*16 + lr;
        bv[nt] = bias[n];
        wv2[nt] = w2[n];
    }
    #pragma unroll
    for (int mt = 0; mt < 4; ++mt)
        #pragma unroll
        for (int r4 = 0; r4 < 4; ++r4) {
            size_t m = (size_t)blockIdx.x*TBM + mq + mt*16 + q*4 + r4;
            float s = 0.f;
            #pragma unroll
            for (int nt = 0; nt < 4; ++nt)
                s += gelu_t(acc[mt][nt][r4] + bv[nt]) * wv2[nt];
            #pragma unroll
            for (int off = 8; off > 0; off >>= 1) s += __shfl_down(s, off, 16);
            if (lr == 0) atomicAdd(&out[m], s);
        }
}

// ---------------- init out with final bias ----------------
__global__ void initout_k(float* __restrict__ out, const float* __restrict__ b2){
    int i = blockIdx.x*blockDim.x + threadIdx.x;
    if (i < M_TOT) out[i] = b2[0];
}

// ---------------- bilinear patch extraction -> fused cols [256..511] (bf16) ----------------
__global__ void patch_k(const float* __restrict__ fmap, const float* __restrict__ points,
                        unsigned short* __restrict__ fused)
{
    int t = blockIdx.x*blockDim.x + threadIdx.x;   // M*64 threads
    int m = t >> 6, ij = t & 63;
    if (m >= M_TOT) return;
    int i = ij >> 3, j = ij & 7;
    int b = m >> 12;
    const int W = 56, H = 56;
    float px = points[m*2], py = points[m*2+1];
    float cx = px*2.f - 1.f, cy = py*2.f - 1.f;
    const float step = 2.0f/55.0f;
    float gx = cx + ((float)i - 3.5f)*step;
    float gy = cy + ((float)j - 3.5f)*step;
    float ix = (gx + 1.f)*0.5f*55.f;
    float iy = (gy + 1.f)*0.5f*55.f;
    float x0f = floorf(ix), y0f = floorf(iy);
    int x0 = (int)x0f, y0 = (int)y0f;
    int x1 = x0 + 1,  y1 = y0 + 1;
    float wx1 = ix - x0f, wx0 = 1.f - wx1;
    float wy1 = iy - y0f, wy0 = 1.f - wy1;
    float v00 = ((x0>=0)&&(x0<W)&&(y0>=0)&&(y0<H)) ? 1.f : 0.f;
    float v10 = ((x1>=0)&&(x1<W)&&(y0>=0)&&(y0<H)) ? 1.f : 0.f;
    float v01 = ((x0>=0)&&(x0<W)&&(y1>=0)&&(y1<H)) ? 1.f : 0.f;
    float v11 = ((x1>=0)&&(x1<W)&&(y1>=0)&&(y1<H)) ? 1.f : 0.f;
    float w00 = wx0*wy0*v00, w10 = wx1*wy0*v10, w01 = wx0*wy1*v01, w11 = wx1*wy1*v11;
    int cx0 = min(max(x0,0),W-1), cx1 = min(max(x1,0),W-1);
    int cy0 = min(max(y0,0),H-1), cy1 = min(max(y1,0),H-1);
    int i00 = cy0*W + cx0, i10 = cy0*W + cx1, i01 = cy1*W + cx0, i11 = cy1*W + cx1;
    #pragma unroll
    for (int c = 0; c < 4; ++c) {
        const float* f = fmap + ((size_t)(b*4 + c))*H*W;
        float v = w00*f[i00] + w10*f[i10] + w01*f[i01] + w11*f[i11];
        fused[(size_t)m*576 + 256 + c*64 + ij] = f2bf(v);
    }
}

// ---------------- broadcast gc [B,64] -> fused cols [512..575] (bf16) ----------------
__global__ void gcbc_k(const float* __restrict__ gc, unsigned short* __restrict__ fused){
    int t = blockIdx.x*blockDim.x + threadIdx.x;   // M*64
    int m = t >> 6, c = t & 63;
    if (m >= M_TOT) return;
    int b = m >> 12;
    fused[(size_t)m*576 + 512 + c] = f2bf(gc[b*64 + c]);
}

extern "C" void kernel_launch(void* const* d_in, const int* in_sizes, int n_in,
                              void* d_out, int out_size, void* d_ws, size_t ws_size,
                              hipStream_t stream) {
    const float* points = (const float*)d_in[0];
    const float* images = (const float*)d_in[1];
    const float* pw1 = (const float*)d_in[2];  const float* pb1 = (const float*)d_in[3];
    const float* pw2 = (const float*)d_in[4];  const float* pb2 = (const float*)d_in[5];
    const float* pw3 = (const float*)d_in[6];  const float* pb3 = (const float*)d_in[7];
    const float* gw1 = (const float*)d_in[8];  const float* gb1 = (const float*)d_in[9];
    const float* gw2 = (const float*)d_in[10]; const float* gb2 = (const float*)d_in[11];
    const float* gw3 = (const float*)d_in[12]; const float* gb3 = (const float*)d_in[13];
    const float* gw4 = (const float*)d_in[14]; const float* gb4 = (const float*)d_in[15];
    const float* gw5 = (const float*)d_in[16]; const float* gb5 = (const float*)d_in[17];
    const float* lw1 = (const float*)d_in[18]; const float* lb1 = (const float*)d_in[19];
    const float* lw2 = (const float*)d_in[20]; const float* lb2 = (const float*)d_in[21];
    const float* hw1 = (const float*)d_in[22]; const float* hb1 = (const float*)d_in[23];
    const float* hw2 = (const float*)d_in[24]; const float* hb2 = (const float*)d_in[25];
    float* out = (float*)d_out;

    // ---- workspace layout ----
    char* base = (char*)d_ws;
    unsigned short* fused_b = (unsigned short*)base;                       // M*576 bf16
    unsigned short* hid_b   = fused_b + (size_t)M_TOT*576;                 // M*256 bf16
    float* fmap = (float*)(hid_b + (size_t)M_TOT*256);                     // 16*4*56*56
    float* gc   = fmap + (size_t)16*4*56*56;                               // 1024
    unsigned short* blw1 = (unsigned short*)(gc + 1024);                   // 256*64
    unsigned short* blw2 = blw1 + 256*64;                                  // 256*256
    unsigned short* bhw1 = blw2 + 256*256;                                 // 512*576
    // aliases inside fused region (dead before gemm2 writes fused):
    unsigned short* pe_b = fused_b;                                        // M*64 bf16
    float* ct = (float*)(base + (size_t)M_TOT*64*2);                       // conv temps
    float* f1 = ct;                                                        // 3,211,264
    float* f2 = f1 + (size_t)16*16*112*112;                                // 1,605,632
    float* g1 = f2 + (size_t)16*32*56*56;                                  //   802,816
    float* g2 = g1 + (size_t)16*4*112*112;                                 //   401,408
    float* g3 = g2 + (size_t)16*8*56*56;                                   //   200,704
    float* g4 = g3 + (size_t)16*16*28*28;                                  //   100,352
    float* g5 = g4 + (size_t)16*32*14*14;                                  //    50,176

    // weight conversions (tiny)
    cvt_pad_lw1_k<<<64, 256, 0, stream>>>(lw1, blw1);
    cvt_bf16_k<<<256, 256, 0, stream>>>(lw2, blw2, 256*256);
    cvt_bf16_k<<<1152, 256, 0, stream>>>(hw1, bhw1, 512*576);
    // plane encoder (LDS-tiled convs)
    conv_tile_k<3,16,2> <<<dim3(7,7,16), 256, 0, stream>>>(images, pw1, pb1, f1,   224,224, 112,112);
    conv_tile_k<16,32,2><<<dim3(4,4,16), 256, 0, stream>>>(f1,     pw2, pb2, f2,   112,112,  56, 56);
    conv_tile_k<32,4,1> <<<dim3(4,4,16), 256, 0, stream>>>(f2,     pw3, pb3, fmap,  56, 56,  56, 56);
    // global encoder
    conv_tile_k<3,4,2>  <<<dim3(7,7,16), 256, 0, stream>>>(images, gw1, gb1, g1,   224,224, 112,112);
    conv_tile_k<4,8,2>  <<<dim3(4,4,16), 256, 0, stream>>>(g1,     gw2, gb2, g2,   112,112,  56, 56);
    conv_tile_k<8,16,2> <<<dim3(2,2,16), 256, 0, stream>>>(g2,     gw3, gb3, g3,    56, 56,  28, 28);
    conv3x3_k<<<dim3(1,1,16*32), dim3(16,16), 0, stream>>>(g3, gw4, gb4, g4, 16, 28, 28, 32, 14, 14, 2);
    conv3x3_k<<<dim3(1,1,16*64), dim3(16,16), 0, stream>>>(g4, gw5, gb5, g5, 32, 14, 14, 64,  7,  7, 2);
    avgpool7_k<<<4, 256, 0, stream>>>(g5, gc);
    // point branch (bf16 MFMA)
    embed_k<<<(M_TOT*64)/256, 256, 0, stream>>>(points, pe_b);
    gemm_bf16_k<<<dim3(M_TOT/TBM, 256/TBN), 256, 0, stream>>>(pe_b,  64,  blw1, 64,  lb1, hid_b,   256, 64,  1);
    gemm_bf16_k<<<dim3(M_TOT/TBM, 256/TBN), 256, 0, stream>>>(hid_b, 256, blw2, 256, lb2, fused_b, 576, 256, 0);
    // patches + global broadcast into fused (bf16)
    patch_k<<<(M_TOT*64)/256, 256, 0, stream>>>(fmap, points, fused_b);
    gcbc_k<<<(M_TOT*64)/256, 256, 0, stream>>>(gc, fused_b);
    // head: MFMA gemm(576->512)+gelu+dot(512->1) fused via atomics
    initout_k<<<M_TOT/256, 256, 0, stream>>>(out, hb2);
    gemm_head_k<<<dim3(M_TOT/TBM, 512/TBN), 256, 0, stream>>>(fused_b, 576, bhw1, 576, hb1, hw2, out, 576);
}

// Round 5
// 507.925 us; speedup vs baseline: 2.4020x; 1.0749x over previous
//
#include <hip/hip_runtime.h>
#include <math.h>

#define BB 16
#define NN 4096
#define M_TOT (BB*NN)   // 65536 points

typedef __attribute__((ext_vector_type(8))) short s8v;   // 8 bf16 = 4 VGPRs
typedef __attribute__((ext_vector_type(4))) float f4v;

// exact tanh-GELU via sigmoid identity: 0.5x(1+tanh(z)) = x * sigmoid(2z)
__device__ __forceinline__ float gelu_t(float x){
    float u = 1.5957691216057308f * x * (1.0f + 0.044715f*x*x);
    return x / (1.0f + __expf(-u));
}

__device__ __forceinline__ unsigned short f2bf(float f){
    unsigned int u = __float_as_uint(f);
    u += 0x7fffu + ((u >> 16) & 1u);
    return (unsigned short)(u >> 16);
}

// ---------------- LDS-tiled conv 3x3, pad 1, GELU epilogue ----------------
template<int CIN, int COUT, int STRIDE>
__global__ __launch_bounds__(256) void conv_tile_k(
    const float* __restrict__ in, const float* __restrict__ w,
    const float* __restrict__ bias, float* __restrict__ out,
    int Hin, int Win, int Hout, int Wout)
{
    constexpr int IW = 15*STRIDE + 3;
    constexpr int IH = IW;
    __shared__ float tile[IH][IW + 1];
    int tid = threadIdx.x;
    int tx = tid & 15, ty = tid >> 4;
    int b = blockIdx.z;
    int wo = blockIdx.x*16 + tx;
    int ho = blockIdx.y*16 + ty;
    int win0 = blockIdx.x*16*STRIDE - 1;
    int hin0 = blockIdx.y*16*STRIDE - 1;
    bool valid = (wo < Wout) && (ho < Hout);

    float acc[COUT];
    #pragma unroll
    for (int co = 0; co < COUT; ++co) acc[co] = bias[co];

    const float* ib = in + (size_t)(b*CIN)*Hin*Win;
    for (int ci = 0; ci < CIN; ++ci) {
        __syncthreads();
        const float* ic = ib + (size_t)ci*Hin*Win;
        for (int idx = tid; idx < IH*IW; idx += 256) {
            int r = idx / IW, c = idx - r*IW;
            int hi = hin0 + r, wi = win0 + c;
            float v = 0.f;
            if ((unsigned)hi < (unsigned)Hin && (unsigned)wi < (unsigned)Win)
                v = ic[hi*Win + wi];
            tile[r][c] = v;
        }
        __syncthreads();
        float vv[9];
        #pragma unroll
        for (int kh = 0; kh < 3; ++kh)
            #pragma unroll
            for (int kw = 0; kw < 3; ++kw)
                vv[kh*3+kw] = tile[ty*STRIDE + kh][tx*STRIDE + kw];
        const float* wc = w + ci*9;
        #pragma unroll
        for (int co = 0; co < COUT; ++co) {
            const float* wp = wc + co*CIN*9;
            #pragma unroll
            for (int k = 0; k < 9; ++k)
                acc[co] = fmaf(vv[k], wp[k], acc[co]);
        }
    }
    if (valid) {
        size_t obase = ((size_t)b*COUT)*Hout*Wout + (size_t)ho*Wout + wo;
        #pragma unroll
        for (int co = 0; co < COUT; ++co)
            out[obase + (size_t)co*Hout*Wout] = gelu_t(acc[co]);
    }
}

// ---------------- fallback scalar conv (tiny tail maps) ----------------
__global__ void conv3x3_k(const float* __restrict__ in, const float* __restrict__ w,
                          const float* __restrict__ bias, float* __restrict__ out,
                          int Cin, int Hin, int Win, int Cout, int Hout, int Wout, int stride)
{
    int wo = blockIdx.x*16 + threadIdx.x;
    int ho = blockIdx.y*16 + threadIdx.y;
    int bc = blockIdx.z;
    int co = bc % Cout, b = bc / Cout;
    if (wo >= Wout || ho >= Hout) return;
    const float* wp = w + co*Cin*9;
    const float* ip = in + (size_t)(b*Cin)*Hin*Win;
    float acc = bias[co];
    int hbase = ho*stride - 1, wbase = wo*stride - 1;
    for (int ci = 0; ci < Cin; ++ci) {
        const float* ic = ip + (size_t)ci*Hin*Win;
        const float* wc = wp + ci*9;
        #pragma unroll
        for (int kh = 0; kh < 3; ++kh) {
            int hi = hbase + kh;
            if ((unsigned)hi >= (unsigned)Hin) continue;
            #pragma unroll
            for (int kw = 0; kw < 3; ++kw) {
                int wi = wbase + kw;
                if ((unsigned)wi >= (unsigned)Win) continue;
                acc = fmaf(ic[hi*Win + wi], wc[kh*3+kw], acc);
            }
        }
    }
    out[(((size_t)b*Cout + co)*Hout + ho)*Wout + wo] = gelu_t(acc);
}

// ---------------- global avg pool 7x7 ----------------
__global__ void avgpool7_k(const float* __restrict__ in, float* __restrict__ out){
    int i = blockIdx.x*blockDim.x + threadIdx.x;
    if (i >= BB*64) return;
    const float* p = in + (size_t)i*49;
    float s = 0.f;
    #pragma unroll
    for (int k = 0; k < 49; ++k) s += p[k];
    out[i] = s * (1.0f/49.0f);
}

// ---------------- embedding: points [M,2] -> pe bf16 [M,64] ----------------
__global__ void embed_k(const float* __restrict__ points, unsigned short* __restrict__ pe){
    int idx = blockIdx.x*blockDim.x + threadIdx.x;
    if (idx >= M_TOT*64) return;
    int m = idx >> 6, e = idx & 63;
    if (e >= 48) { pe[idx] = 0; return; }
    int i = e >> 2, r = e & 3;
    float f = (float)(1 << i);
    float p = points[m*2 + (r & 1)];
    float s = f * p;
    pe[idx] = f2bf((r < 2) ? __sinf(s) : __cosf(s));
}

// ---------------- fused weight conversions (lw1 pad + lw2 + hw1) ----------------
__global__ void cvtall_k(const float* __restrict__ lw1, const float* __restrict__ lw2,
                         const float* __restrict__ hw1, unsigned short* __restrict__ blw1,
                         unsigned short* __restrict__ blw2, unsigned short* __restrict__ bhw1){
    int i = blockIdx.x*blockDim.x + threadIdx.x;
    if (i < 256*64) {
        int r = i >> 6, c = i & 63;
        blw1[i] = (c < 48) ? f2bf(lw1[r*48 + c]) : 0;
        return;
    }
    i -= 256*64;
    if (i < 256*256) { blw2[i] = f2bf(lw2[i]); return; }
    i -= 256*256;
    if (i < 512*576) bhw1[i] = f2bf(hw1[i]);
}

// ================= bf16 MFMA GEMMs, swizzled staging =================
// LDS chunk fi (16B) holds A[row=fi>>2][k0 + seg_log*8..+7], seg_log=(fi&3)^((fi>>3)&3).
// Fragment read: lane(lr,q) reads chunk (row, q^((lr>>1)&3)) -> 2-way banks (free).
#define TBM 128
#define TBN 128
#define TBK 32

#define GLL(src, dst) __builtin_amdgcn_global_load_lds( \
    (const __attribute__((address_space(1))) void*)(src), \
    (__attribute__((address_space(3))) void*)(dst), 16, 0, 0)

__global__ __launch_bounds__(256) void gemm_bf16_k(
    const unsigned short* __restrict__ A, int lda,
    const unsigned short* __restrict__ W, int ldw,
    const float* __restrict__ bias,
    unsigned short* __restrict__ C, int ldc, int K, int act)
{
    __shared__ unsigned short As[TBM*TBK];
    __shared__ unsigned short Bs[TBN*TBK];
    int tid = threadIdx.x;
    int wv = tid >> 6, lane = tid & 63;
    int q = lane >> 4, lr = lane & 15;
    int sw = q ^ ((lr >> 1) & 3);          // phys seg for fragment reads
    int mq = (wv >> 1) * 64, nq = (wv & 1) * 64;
    const unsigned short* Ab = A + (size_t)blockIdx.y * TBM * lda;
    const unsigned short* Wb = W + (size_t)blockIdx.x * TBN * ldw;

    int fi0 = wv*64 + lane, fi1 = fi0 + 256;
    int r0 = fi0 >> 2, s0 = (fi0 & 3) ^ ((fi0 >> 3) & 3);
    int r1 = fi1 >> 2, s1 = (fi1 & 3) ^ ((fi1 >> 3) & 3);
    const unsigned short* sA0 = Ab + (size_t)r0*lda + s0*8;
    const unsigned short* sA1 = Ab + (size_t)r1*lda + s1*8;
    const unsigned short* sB0 = Wb + (size_t)r0*ldw + s0*8;
    const unsigned short* sB1 = Wb + (size_t)r1*ldw + s1*8;
    unsigned short* dA0 = As + wv*512;     unsigned short* dA1 = As + (4+wv)*512;
    unsigned short* dB0 = Bs + wv*512;     unsigned short* dB1 = Bs + (4+wv)*512;

    f4v acc[4][4];
    #pragma unroll
    for (int i = 0; i < 4; ++i)
        #pragma unroll
        for (int j = 0; j < 4; ++j) acc[i][j] = (f4v){0.f,0.f,0.f,0.f};

    for (int k0 = 0; k0 < K; k0 += TBK) {
        GLL(sA0, dA0); GLL(sA1, dA1); GLL(sB0, dB0); GLL(sB1, dB1);
        sA0 += TBK; sA1 += TBK; sB0 += TBK; sB1 += TBK;
        __syncthreads();
        s8v a[4], b[4];
        #pragma unroll
        for (int t = 0; t < 4; ++t) {
            a[t] = *(const s8v*)(As + (mq + t*16 + lr)*TBK + sw*8);
            b[t] = *(const s8v*)(Bs + (nq + t*16 + lr)*TBK + sw*8);
        }
        #pragma unroll
        for (int mt = 0; mt < 4; ++mt)
            #pragma unroll
            for (int nt = 0; nt < 4; ++nt)
                acc[mt][nt] = __builtin_amdgcn_mfma_f32_16x16x32_bf16(a[mt], b[nt], acc[mt][nt], 0, 0, 0);
        __syncthreads();
    }
    #pragma unroll
    for (int mt = 0; mt < 4; ++mt)
        #pragma unroll
        for (int r4 = 0; r4 < 4; ++r4) {
            size_t m = (size_t)blockIdx.y*TBM + mq + mt*16 + q*4 + r4;
            #pragma unroll
            for (int nt = 0; nt < 4; ++nt) {
                int n = blockIdx.x*TBN + nq + nt*16 + lr;
                float v = acc[mt][nt][r4] + bias[n];
                if (act) v = gelu_t(v);
                C[m*ldc + n] = f2bf(v);
            }
        }
}

// ---------------- head: gemm(576->512)+gelu fused with dot(512->1) ----------------
__global__ __launch_bounds__(256) void gemm_head_k(
    const unsigned short* __restrict__ A, int lda,
    const unsigned short* __restrict__ W, int ldw,
    const float* __restrict__ bias, const float* __restrict__ w2,
    float* __restrict__ out, int K)
{
    __shared__ unsigned short As[TBM*TBK];
    __shared__ unsigned short Bs[TBN*TBK];
    int tid = threadIdx.x;
    int wv = tid >> 6, lane = tid & 63;
    int q = lane >> 4, lr = lane & 15;
    int sw = q ^ ((lr >> 1) & 3);
    int mq = (wv >> 1) * 64, nq = (wv & 1) * 64;
    const unsigned short* Ab = A + (size_t)blockIdx.y * TBM * lda;
    const unsigned short* Wb = W + (size_t)blockIdx.x * TBN * ldw;

    int fi0 = wv*64 + lane, fi1 = fi0 + 256;
    int r0 = fi0 >> 2, s0 = (fi0 & 3) ^ ((fi0 >> 3) & 3);
    int r1 = fi1 >> 2, s1 = (fi1 & 3) ^ ((fi1 >> 3) & 3);
    const unsigned short* sA0 = Ab + (size_t)r0*lda + s0*8;
    const unsigned short* sA1 = Ab + (size_t)r1*lda + s1*8;
    const unsigned short* sB0 = Wb + (size_t)r0*ldw + s0*8;
    const unsigned short* sB1 = Wb + (size_t)r1*ldw + s1*8;
    unsigned short* dA0 = As + wv*512;     unsigned short* dA1 = As + (4+wv)*512;
    unsigned short* dB0 = Bs + wv*512;     unsigned short* dB1 = Bs + (4+wv)*512;

    f4v acc[4][4];
    #pragma unroll
    for (int i = 0; i < 4; ++i)
        #pragma unroll
        for (int j = 0; j < 4; ++j) acc[i][j] = (f4v){0.f,0.f,0.f,0.f};

    for (int k0 = 0; k0 < K; k0 += TBK) {
        GLL(sA0, dA0); GLL(sA1, dA1); GLL(sB0, dB0); GLL(sB1, dB1);
        sA0 += TBK; sA1 += TBK; sB0 += TBK; sB1 += TBK;
        __syncthreads();
        s8v a[4], b[4];
        #pragma unroll
        for (int t = 0; t < 4; ++t) {
            a[t] = *(const s8v*)(As + (mq + t*16 + lr)*TBK + sw*8);
            b[t] = *(const s8v*)(Bs + (nq + t*16 + lr)*TBK + sw*8);
        }
        #pragma unroll
        for (int mt = 0; mt < 4; ++mt)
            #pragma unroll
            for (int nt = 0; nt < 4; ++nt)
                acc[mt][nt] = __builtin_amdgcn_mfma_f32_16x16x32_bf16(a[mt], b[nt], acc[mt][nt], 0, 0, 0);
        __syncthreads();
    }
    float bv[4], wv2[4];
    #pragma unroll
    for (int nt = 0; nt < 4; ++nt) {
        int n = blockIdx.x*TBN + nq + nt*16 + lr;
        bv[nt] = bias[n];
        wv2[nt] = w2[n];
    }
    #pragma unroll
    for (int mt = 0; mt < 4; ++mt)
        #pragma unroll
        for (int r4 = 0; r4 < 4; ++r4) {
            size_t m = (size_t)blockIdx.y*TBM + mq + mt*16 + q*4 + r4;
            float s = 0.f;
            #pragma unroll
            for (int nt = 0; nt < 4; ++nt)
                s += gelu_t(acc[mt][nt][r4] + bv[nt]) * wv2[nt];
            #pragma unroll
            for (int off = 8; off > 0; off >>= 1) s += __shfl_down(s, off, 16);
            if (lr == 0) atomicAdd(&out[m], s);
        }
}

// ---------------- fused: patch gather + gc broadcast + out init ----------------
__global__ void fill_k(const float* __restrict__ fmap, const float* __restrict__ points,
                       const float* __restrict__ gc, const float* __restrict__ b2,
                       unsigned short* __restrict__ fused, float* __restrict__ out)
{
    int t = blockIdx.x*blockDim.x + threadIdx.x;   // M*64 threads
    int m = t >> 6, ij = t & 63;
    if (m >= M_TOT) return;
    int i = ij >> 3, j = ij & 7;
    int b = m >> 12;
    const int W = 56, H = 56;
    float px = points[m*2], py = points[m*2+1];
    float cx = px*2.f - 1.f, cy = py*2.f - 1.f;
    const float step = 2.0f/55.0f;
    float gx = cx + ((float)i - 3.5f)*step;
    float gy = cy + ((float)j - 3.5f)*step;
    float ix = (gx + 1.f)*0.5f*55.f;
    float iy = (gy + 1.f)*0.5f*55.f;
    float x0f = floorf(ix), y0f = floorf(iy);
    int x0 = (int)x0f, y0 = (int)y0f;
    int x1 = x0 + 1,  y1 = y0 + 1;
    float wx1 = ix - x0f, wx0 = 1.f - wx1;
    float wy1 = iy - y0f, wy0 = 1.f - wy1;
    float v00 = ((x0>=0)&&(x0<W)&&(y0>=0)&&(y0<H)) ? 1.f : 0.f;
    float v10 = ((x1>=0)&&(x1<W)&&(y0>=0)&&(y0<H)) ? 1.f : 0.f;
    float v01 = ((x0>=0)&&(x0<W)&&(y1>=0)&&(y1<H)) ? 1.f : 0.f;
    float v11 = ((x1>=0)&&(x1<W)&&(y1>=0)&&(y1<H)) ? 1.f : 0.f;
    float w00 = wx0*wy0*v00, w10 = wx1*wy0*v10, w01 = wx0*wy1*v01, w11 = wx1*wy1*v11;
    int cx0 = min(max(x0,0),W-1), cx1 = min(max(x1,0),W-1);
    int cy0 = min(max(y0,0),H-1), cy1 = min(max(y1,0),H-1);
    int i00 = cy0*W + cx0, i10 = cy0*W + cx1, i01 = cy1*W + cx0, i11 = cy1*W + cx1;
    #pragma unroll
    for (int c = 0; c < 4; ++c) {
        const float* f = fmap + ((size_t)(b*4 + c))*H*W;
        float v = w00*f[i00] + w10*f[i10] + w01*f[i01] + w11*f[i11];
        fused[(size_t)m*576 + 256 + c*64 + ij] = f2bf(v);
    }
    fused[(size_t)m*576 + 512 + ij] = f2bf(gc[b*64 + ij]);
    if (ij == 0) out[m] = b2[0];
}

extern "C" void kernel_launch(void* const* d_in, const int* in_sizes, int n_in,
                              void* d_out, int out_size, void* d_ws, size_t ws_size,
                              hipStream_t stream) {
    const float* points = (const float*)d_in[0];
    const float* images = (const float*)d_in[1];
    const float* pw1 = (const float*)d_in[2];  const float* pb1 = (const float*)d_in[3];
    const float* pw2 = (const float*)d_in[4];  const float* pb2 = (const float*)d_in[5];
    const float* pw3 = (const float*)d_in[6];  const float* pb3 = (const float*)d_in[7];
    const float* gw1 = (const float*)d_in[8];  const float* gb1 = (const float*)d_in[9];
    const float* gw2 = (const float*)d_in[10]; const float* gb2 = (const float*)d_in[11];
    const float* gw3 = (const float*)d_in[12]; const float* gb3 = (const float*)d_in[13];
    const float* gw4 = (const float*)d_in[14]; const float* gb4 = (const float*)d_in[15];
    const float* gw5 = (const float*)d_in[16]; const float* gb5 = (const float*)d_in[17];
    const float* lw1 = (const float*)d_in[18]; const float* lb1 = (const float*)d_in[19];
    const float* lw2 = (const float*)d_in[20]; const float* lb2 = (const float*)d_in[21];
    const float* hw1 = (const float*)d_in[22]; const float* hb1 = (const float*)d_in[23];
    const float* hw2 = (const float*)d_in[24]; const float* hb2 = (const float*)d_in[25];
    float* out = (float*)d_out;

    // ---- workspace layout ----
    char* base = (char*)d_ws;
    unsigned short* fused_b = (unsigned short*)base;                       // M*576 bf16
    unsigned short* hid_b   = fused_b + (size_t)M_TOT*576;                 // M*256 bf16
    float* fmap = (float*)(hid_b + (size_t)M_TOT*256);                     // 16*4*56*56
    float* gc   = fmap + (size_t)16*4*56*56;                               // 1024
    unsigned short* blw1 = (unsigned short*)(gc + 1024);                   // 256*64
    unsigned short* blw2 = blw1 + 256*64;                                  // 256*256
    unsigned short* bhw1 = blw2 + 256*256;                                 // 512*576
    // aliases inside fused region (dead before gemm2 writes fused):
    unsigned short* pe_b = fused_b;                                        // M*64 bf16
    float* ct = (float*)(base + (size_t)M_TOT*64*2);                       // conv temps
    float* f1 = ct;
    float* f2 = f1 + (size_t)16*16*112*112;
    float* g1 = f2 + (size_t)16*32*56*56;
    float* g2 = g1 + (size_t)16*4*112*112;
    float* g3 = g2 + (size_t)16*8*56*56;
    float* g4 = g3 + (size_t)16*16*28*28;
    float* g5 = g4 + (size_t)16*32*14*14;

    cvtall_k<<<1472, 256, 0, stream>>>(lw1, lw2, hw1, blw1, blw2, bhw1);
    // plane encoder
    conv_tile_k<3,16,2> <<<dim3(7,7,16), 256, 0, stream>>>(images, pw1, pb1, f1,   224,224, 112,112);
    conv_tile_k<16,32,2><<<dim3(4,4,16), 256, 0, stream>>>(f1,     pw2, pb2, f2,   112,112,  56, 56);
    conv_tile_k<32,4,1> <<<dim3(4,4,16), 256, 0, stream>>>(f2,     pw3, pb3, fmap,  56, 56,  56, 56);
    // global encoder
    conv_tile_k<3,4,2>  <<<dim3(7,7,16), 256, 0, stream>>>(images, gw1, gb1, g1,   224,224, 112,112);
    conv_tile_k<4,8,2>  <<<dim3(4,4,16), 256, 0, stream>>>(g1,     gw2, gb2, g2,   112,112,  56, 56);
    conv_tile_k<8,16,2> <<<dim3(2,2,16), 256, 0, stream>>>(g2,     gw3, gb3, g3,    56, 56,  28, 28);
    conv3x3_k<<<dim3(1,1,16*32), dim3(16,16), 0, stream>>>(g3, gw4, gb4, g4, 16, 28, 28, 32, 14, 14, 2);
    conv3x3_k<<<dim3(1,1,16*64), dim3(16,16), 0, stream>>>(g4, gw5, gb5, g5, 32, 14, 14, 64,  7,  7, 2);
    avgpool7_k<<<4, 256, 0, stream>>>(g5, gc);
    // point branch (bf16 MFMA) — grid: x = N-chunks (A-tile reuse), y = M-chunks
    embed_k<<<(M_TOT*64)/256, 256, 0, stream>>>(points, pe_b);
    gemm_bf16_k<<<dim3(256/TBN, M_TOT/TBM), 256, 0, stream>>>(pe_b,  64,  blw1, 64,  lb1, hid_b,   256, 64,  1);
    gemm_bf16_k<<<dim3(256/TBN, M_TOT/TBM), 256, 0, stream>>>(hid_b, 256, blw2, 256, lb2, fused_b, 576, 256, 0);
    // patches + gc broadcast + out-bias init (fused)
    fill_k<<<(M_TOT*64)/256, 256, 0, stream>>>(fmap, points, gc, hb2, fused_b, out);
    // head: MFMA gemm(576->512)+gelu+dot(512->1) fused via atomics
    gemm_head_k<<<dim3(512/TBN, M_TOT/TBM), 256, 0, stream>>>(fused_b, 576, bhw1, 576, hb1, hw2, out, 576);
}

// Round 6
// 504.855 us; speedup vs baseline: 2.4166x; 1.0061x over previous
//
#include <hip/hip_runtime.h>
#include <math.h>

#define BB 16
#define NN 4096
#define M_TOT (BB*NN)   // 65536 points
#define TBK 32

typedef __attribute__((ext_vector_type(8))) short s8v;   // 8 bf16 = 4 VGPRs
typedef __attribute__((ext_vector_type(4))) float f4v;

// exact tanh-GELU via sigmoid identity: 0.5x(1+tanh(z)) = x * sigmoid(2z)
__device__ __forceinline__ float gelu_t(float x){
    float u = 1.5957691216057308f * x * (1.0f + 0.044715f*x*x);
    return x / (1.0f + __expf(-u));
}

__device__ __forceinline__ unsigned short f2bf(float f){
    unsigned int u = __float_as_uint(f);
    u += 0x7fffu + ((u >> 16) & 1u);
    return (unsigned short)(u >> 16);
}

#define GLL(src, dst) __builtin_amdgcn_global_load_lds( \
    (const __attribute__((address_space(1))) void*)(src), \
    (__attribute__((address_space(3))) void*)(dst), 16, 0, 0)

// ---------------- LDS-tiled conv 3x3, pad 1, GELU epilogue ----------------
template<int CIN, int COUT, int STRIDE>
__global__ __launch_bounds__(256) void conv_tile_k(
    const float* __restrict__ in, const float* __restrict__ w,
    const float* __restrict__ bias, float* __restrict__ out,
    int Hin, int Win, int Hout, int Wout)
{
    constexpr int IW = 15*STRIDE + 3;
    constexpr int IH = IW;
    __shared__ float tile[IH][IW + 1];
    int tid = threadIdx.x;
    int tx = tid & 15, ty = tid >> 4;
    int b = blockIdx.z;
    int wo = blockIdx.x*16 + tx;
    int ho = blockIdx.y*16 + ty;
    int win0 = blockIdx.x*16*STRIDE - 1;
    int hin0 = blockIdx.y*16*STRIDE - 1;
    bool valid = (wo < Wout) && (ho < Hout);

    float acc[COUT];
    #pragma unroll
    for (int co = 0; co < COUT; ++co) acc[co] = bias[co];

    const float* ib = in + (size_t)(b*CIN)*Hin*Win;
    for (int ci = 0; ci < CIN; ++ci) {
        __syncthreads();
        const float* ic = ib + (size_t)ci*Hin*Win;
        for (int idx = tid; idx < IH*IW; idx += 256) {
            int r = idx / IW, c = idx - r*IW;
            int hi = hin0 + r, wi = win0 + c;
            float v = 0.f;
            if ((unsigned)hi < (unsigned)Hin && (unsigned)wi < (unsigned)Win)
                v = ic[hi*Win + wi];
            tile[r][c] = v;
        }
        __syncthreads();
        float vv[9];
        #pragma unroll
        for (int kh = 0; kh < 3; ++kh)
            #pragma unroll
            for (int kw = 0; kw < 3; ++kw)
                vv[kh*3+kw] = tile[ty*STRIDE + kh][tx*STRIDE + kw];
        const float* wc = w + ci*9;
        #pragma unroll
        for (int co = 0; co < COUT; ++co) {
            const float* wp = wc + co*CIN*9;
            #pragma unroll
            for (int k = 0; k < 9; ++k)
                acc[co] = fmaf(vv[k], wp[k], acc[co]);
        }
    }
    if (valid) {
        size_t obase = ((size_t)b*COUT)*Hout*Wout + (size_t)ho*Wout + wo;
        #pragma unroll
        for (int co = 0; co < COUT; ++co)
            out[obase + (size_t)co*Hout*Wout] = gelu_t(acc[co]);
    }
}

// ---------------- fallback scalar conv (tiny tail maps) ----------------
__global__ void conv3x3_k(const float* __restrict__ in, const float* __restrict__ w,
                          const float* __restrict__ bias, float* __restrict__ out,
                          int Cin, int Hin, int Win, int Cout, int Hout, int Wout, int stride)
{
    int wo = blockIdx.x*16 + threadIdx.x;
    int ho = blockIdx.y*16 + threadIdx.y;
    int bc = blockIdx.z;
    int co = bc % Cout, b = bc / Cout;
    if (wo >= Wout || ho >= Hout) return;
    const float* wp = w + co*Cin*9;
    const float* ip = in + (size_t)(b*Cin)*Hin*Win;
    float acc = bias[co];
    int hbase = ho*stride - 1, wbase = wo*stride - 1;
    for (int ci = 0; ci < Cin; ++ci) {
        const float* ic = ip + (size_t)ci*Hin*Win;
        const float* wc = wp + ci*9;
        #pragma unroll
        for (int kh = 0; kh < 3; ++kh) {
            int hi = hbase + kh;
            if ((unsigned)hi >= (unsigned)Hin) continue;
            #pragma unroll
            for (int kw = 0; kw < 3; ++kw) {
                int wi = wbase + kw;
                if ((unsigned)wi >= (unsigned)Win) continue;
                acc = fmaf(ic[hi*Win + wi], wc[kh*3+kw], acc);
            }
        }
    }
    out[(((size_t)b*Cout + co)*Hout + ho)*Wout + wo] = gelu_t(acc);
}

// ---------------- global avg pool 7x7 ----------------
__global__ void avgpool7_k(const float* __restrict__ in, float* __restrict__ out){
    int i = blockIdx.x*blockDim.x + threadIdx.x;
    if (i >= BB*64) return;
    const float* p = in + (size_t)i*49;
    float s = 0.f;
    #pragma unroll
    for (int k = 0; k < 49; ++k) s += p[k];
    out[i] = s * (1.0f/49.0f);
}

// ---------------- fused weight conversions (lw1 pad + lw2 + hw1) ----------------
__global__ void cvtall_k(const float* __restrict__ lw1, const float* __restrict__ lw2,
                         const float* __restrict__ hw1, unsigned short* __restrict__ blw1,
                         unsigned short* __restrict__ blw2, unsigned short* __restrict__ bhw1){
    int i = blockIdx.x*blockDim.x + threadIdx.x;
    if (i < 256*64) {
        int r = i >> 6, c = i & 63;
        blw1[i] = (c < 48) ? f2bf(lw1[r*48 + c]) : 0;
        return;
    }
    i -= 256*64;
    if (i < 256*256) { blw2[i] = f2bf(lw2[i]); return; }
    i -= 256*256;
    if (i < 512*576) bhw1[i] = f2bf(hw1[i]);
}

// ================= full-N bf16 MFMA GEMM =================
// Block: 256 threads, M-strip 64, covers ALL N = NWT*64 columns.
// Wave wv covers n in [wv*NWT*16, (wv+1)*NWT*16). 4 m-tiles x NWT n-tiles.
// Swizzled staging (TBK=32, 4 chunks/row): chunk fi holds row fi>>2,
// logical seg (fi&3)^((fi>>3)&3); frag read at phys seg q^((lr>>1)&3).
template<int NWT>
__global__ __launch_bounds__(256) void gemm_fn_k(
    const unsigned short* __restrict__ A, int lda,
    const unsigned short* __restrict__ W, int ldw,
    const float* __restrict__ bias,
    unsigned short* __restrict__ C, int ldc, int K, int act)
{
    constexpr int NB = NWT*64;
    constexpr int NCH = NB/64;            // B chunks per thread
    __shared__ unsigned short As[64*TBK];
    __shared__ unsigned short Bs[NB*TBK];
    int tid = threadIdx.x;
    int wv = tid >> 6, lane = tid & 63;
    int q = lane >> 4, lr = lane & 15;
    int sw = q ^ ((lr >> 1) & 3);
    int nqw = wv*NWT*16;
    const unsigned short* Ab = A + (size_t)blockIdx.x*64*lda;

    int rA = tid >> 2, sA = (tid & 3) ^ ((tid >> 3) & 3);
    const unsigned short* srcA = Ab + (size_t)rA*lda + sA*8;
    unsigned short* dstA = As + tid*8;
    const unsigned short* srcB[NCH];
    unsigned short* dstB[NCH];
    #pragma unroll
    for (int r = 0; r < NCH; ++r) {
        int f = r*256 + tid;
        int rr = f >> 2, ss = (f & 3) ^ ((f >> 3) & 3);
        srcB[r] = W + (size_t)rr*ldw + ss*8;
        dstB[r] = Bs + f*8;
    }

    f4v acc[4][NWT];
    #pragma unroll
    for (int i = 0; i < 4; ++i)
        #pragma unroll
        for (int j = 0; j < NWT; ++j) acc[i][j] = (f4v){0.f,0.f,0.f,0.f};

    for (int k0 = 0; k0 < K; k0 += TBK) {
        GLL(srcA, dstA); srcA += TBK;
        #pragma unroll
        for (int r = 0; r < NCH; ++r) { GLL(srcB[r], dstB[r]); srcB[r] += TBK; }
        __syncthreads();
        s8v a[4], b[NWT];
        #pragma unroll
        for (int t = 0; t < 4; ++t)
            a[t] = *(const s8v*)(As + (t*16 + lr)*TBK + sw*8);
        #pragma unroll
        for (int t = 0; t < NWT; ++t)
            b[t] = *(const s8v*)(Bs + (nqw + t*16 + lr)*TBK + sw*8);
        #pragma unroll
        for (int mt = 0; mt < 4; ++mt)
            #pragma unroll
            for (int nt = 0; nt < NWT; ++nt)
                acc[mt][nt] = __builtin_amdgcn_mfma_f32_16x16x32_bf16(a[mt], b[nt], acc[mt][nt], 0, 0, 0);
        __syncthreads();
    }
    #pragma unroll
    for (int mt = 0; mt < 4; ++mt)
        #pragma unroll
        for (int r4 = 0; r4 < 4; ++r4) {
            size_t m = (size_t)blockIdx.x*64 + mt*16 + q*4 + r4;
            #pragma unroll
            for (int nt = 0; nt < NWT; ++nt) {
                int n = nqw + nt*16 + lr;
                float v = acc[mt][nt][r4] + bias[n];
                if (act) v = gelu_t(v);
                C[m*ldc + n] = f2bf(v);
            }
        }
}

// ---------------- head: full-N gemm(576->512)+gelu + dot(512->1), direct store ----------------
__global__ __launch_bounds__(256, 2) void gemm_hd_k(
    const unsigned short* __restrict__ A, int lda,
    const unsigned short* __restrict__ W, int ldw,
    const float* __restrict__ bias, const float* __restrict__ w2,
    const float* __restrict__ b2, float* __restrict__ out, int K)
{
    constexpr int NWT = 8;
    constexpr int NB = 512;
    constexpr int NCH = 8;
    __shared__ unsigned short As[64*TBK];
    __shared__ unsigned short Bs[NB*TBK];
    __shared__ float red[4*64];
    int tid = threadIdx.x;
    int wv = tid >> 6, lane = tid & 63;
    int q = lane >> 4, lr = lane & 15;
    int sw = q ^ ((lr >> 1) & 3);
    int nqw = wv*128;
    const unsigned short* Ab = A + (size_t)blockIdx.x*64*lda;

    int rA = tid >> 2, sA = (tid & 3) ^ ((tid >> 3) & 3);
    const unsigned short* srcA = Ab + (size_t)rA*lda + sA*8;
    unsigned short* dstA = As + tid*8;
    const unsigned short* srcB[NCH];
    unsigned short* dstB[NCH];
    #pragma unroll
    for (int r = 0; r < NCH; ++r) {
        int f = r*256 + tid;
        int rr = f >> 2, ss = (f & 3) ^ ((f >> 3) & 3);
        srcB[r] = W + (size_t)rr*ldw + ss*8;
        dstB[r] = Bs + f*8;
    }

    f4v acc[4][NWT];
    #pragma unroll
    for (int i = 0; i < 4; ++i)
        #pragma unroll
        for (int j = 0; j < NWT; ++j) acc[i][j] = (f4v){0.f,0.f,0.f,0.f};

    for (int k0 = 0; k0 < K; k0 += TBK) {
        GLL(srcA, dstA); srcA += TBK;
        #pragma unroll
        for (int r = 0; r < NCH; ++r) { GLL(srcB[r], dstB[r]); srcB[r] += TBK; }
        __syncthreads();
        s8v a[4], b[NWT];
        #pragma unroll
        for (int t = 0; t < 4; ++t)
            a[t] = *(const s8v*)(As + (t*16 + lr)*TBK + sw*8);
        #pragma unroll
        for (int t = 0; t < NWT; ++t)
            b[t] = *(const s8v*)(Bs + (nqw + t*16 + lr)*TBK + sw*8);
        #pragma unroll
        for (int mt = 0; mt < 4; ++mt)
            #pragma unroll
            for (int nt = 0; nt < NWT; ++nt)
                acc[mt][nt] = __builtin_amdgcn_mfma_f32_16x16x32_bf16(a[mt], b[nt], acc[mt][nt], 0, 0, 0);
        __syncthreads();
    }
    // epilogue: per-wave partial dot over its 128 n-columns
    float bv[NWT], wv2[NWT];
    #pragma unroll
    for (int nt = 0; nt < NWT; ++nt) {
        int n = nqw + nt*16 + lr;
        bv[nt] = bias[n];
        wv2[nt] = w2[n];
    }
    #pragma unroll
    for (int mt = 0; mt < 4; ++mt)
        #pragma unroll
        for (int r4 = 0; r4 < 4; ++r4) {
            int ml = mt*16 + q*4 + r4;
            float s = 0.f;
            #pragma unroll
            for (int nt = 0; nt < NWT; ++nt)
                s += gelu_t(acc[mt][nt][r4] + bv[nt]) * wv2[nt];
            #pragma unroll
            for (int off = 8; off > 0; off >>= 1) s += __shfl_down(s, off, 16);
            if (lr == 0) red[wv*64 + ml] = s;
        }
    __syncthreads();
    if (tid < 64) {
        float t = red[tid] + red[64 + tid] + red[128 + tid] + red[192 + tid];
        out[blockIdx.x*64 + tid] = t + b2[0];
    }
}

// ---------------- mlp1 fused with embedding: points -> gelu(pe@lw1^T+b) ----------------
// K=64 (48 real + 16 zero-pad), N=256. A computed in-kernel into LDS.
// LDS layout: 8 chunks (16B) per row; chunk (row,pp) holds logical seg pp^(row&7).
__global__ __launch_bounds__(256) void mlp1_k(
    const float* __restrict__ points, const unsigned short* __restrict__ W,
    const float* __restrict__ bias, unsigned short* __restrict__ C)
{
    __shared__ unsigned short As[64*64];
    __shared__ unsigned short Bs[256*64];
    int tid = threadIdx.x;
    int wv = tid >> 6, lane = tid & 63;
    int q = lane >> 4, lr = lane & 15;
    int nqw = wv*64;

    // stage B (lw1 padded 256x64) once: 2048 chunks, 8 per thread
    #pragma unroll
    for (int r = 0; r < 8; ++r) {
        int c = r*256 + tid;
        int row = c >> 3, pp = c & 7, pl = pp ^ (row & 7);
        GLL(W + row*64 + pl*8, Bs + c*8);
    }
    // compute A (embedding) into LDS: 512 chunks, 2 per thread
    #pragma unroll
    for (int r = 0; r < 2; ++r) {
        int c = r*256 + tid;
        int row = c >> 3, pp = c & 7, pl = pp ^ (row & 7);
        int m = blockIdx.x*64 + row;
        float px = points[m*2], py = points[m*2+1];
        union { s8v v; unsigned short u[8]; } pk;
        #pragma unroll
        for (int j = 0; j < 8; ++j) {
            int k = pl*8 + j;
            unsigned short val = 0;
            if (k < 48) {
                int i = k >> 2, rr = k & 3;
                float f = (float)(1 << i);
                float p = (rr & 1) ? py : px;
                float s = f * p;
                val = f2bf((rr < 2) ? __sinf(s) : __cosf(s));
            }
            pk.u[j] = val;
        }
        *(s8v*)(As + c*8) = pk.v;
    }
    __syncthreads();

    f4v acc[4][4];
    #pragma unroll
    for (int i = 0; i < 4; ++i)
        #pragma unroll
        for (int j = 0; j < 4; ++j) acc[i][j] = (f4v){0.f,0.f,0.f,0.f};

    #pragma unroll
    for (int kb = 0; kb < 2; ++kb) {
        s8v a[4], b[4];
        #pragma unroll
        for (int t = 0; t < 4; ++t) {
            int row = t*16 + lr;
            int pp = (kb*4 + q) ^ (row & 7);
            a[t] = *(const s8v*)(As + row*64 + pp*8);
        }
        #pragma unroll
        for (int t = 0; t < 4; ++t) {
            int row = nqw + t*16 + lr;
            int pp = (kb*4 + q) ^ (row & 7);
            b[t] = *(const s8v*)(Bs + row*64 + pp*8);
        }
        #pragma unroll
        for (int mt = 0; mt < 4; ++mt)
            #pragma unroll
            for (int nt = 0; nt < 4; ++nt)
                acc[mt][nt] = __builtin_amdgcn_mfma_f32_16x16x32_bf16(a[mt], b[nt], acc[mt][nt], 0, 0, 0);
    }
    #pragma unroll
    for (int mt = 0; mt < 4; ++mt)
        #pragma unroll
        for (int r4 = 0; r4 < 4; ++r4) {
            size_t m = (size_t)blockIdx.x*64 + mt*16 + q*4 + r4;
            #pragma unroll
            for (int nt = 0; nt < 4; ++nt) {
                int n = nqw + nt*16 + lr;
                C[m*256 + n] = f2bf(gelu_t(acc[mt][nt][r4] + bias[n]));
            }
        }
}

// ---------------- fused: patch gather + gc broadcast ----------------
__global__ void fill_k(const float* __restrict__ fmap, const float* __restrict__ points,
                       const float* __restrict__ gc, unsigned short* __restrict__ fused)
{
    int t = blockIdx.x*blockDim.x + threadIdx.x;   // M*64 threads
    int m = t >> 6, ij = t & 63;
    if (m >= M_TOT) return;
    int i = ij >> 3, j = ij & 7;
    int b = m >> 12;
    const int W = 56, H = 56;
    float px = points[m*2], py = points[m*2+1];
    float cx = px*2.f - 1.f, cy = py*2.f - 1.f;
    const float step = 2.0f/55.0f;
    float gx = cx + ((float)i - 3.5f)*step;
    float gy = cy + ((float)j - 3.5f)*step;
    float ix = (gx + 1.f)*0.5f*55.f;
    float iy = (gy + 1.f)*0.5f*55.f;
    float x0f = floorf(ix), y0f = floorf(iy);
    int x0 = (int)x0f, y0 = (int)y0f;
    int x1 = x0 + 1,  y1 = y0 + 1;
    float wx1 = ix - x0f, wx0 = 1.f - wx1;
    float wy1 = iy - y0f, wy0 = 1.f - wy1;
    float v00 = ((x0>=0)&&(x0<W)&&(y0>=0)&&(y0<H)) ? 1.f : 0.f;
    float v10 = ((x1>=0)&&(x1<W)&&(y0>=0)&&(y0<H)) ? 1.f : 0.f;
    float v01 = ((x0>=0)&&(x0<W)&&(y1>=0)&&(y1<H)) ? 1.f : 0.f;
    float v11 = ((x1>=0)&&(x1<W)&&(y1>=0)&&(y1<H)) ? 1.f : 0.f;
    float w00 = wx0*wy0*v00, w10 = wx1*wy0*v10, w01 = wx0*wy1*v01, w11 = wx1*wy1*v11;
    int cx0 = min(max(x0,0),W-1), cx1 = min(max(x1,0),W-1);
    int cy0 = min(max(y0,0),H-1), cy1 = min(max(y1,0),H-1);
    int i00 = cy0*W + cx0, i10 = cy0*W + cx1, i01 = cy1*W + cx0, i11 = cy1*W + cx1;
    #pragma unroll
    for (int c = 0; c < 4; ++c) {
        const float* f = fmap + ((size_t)(b*4 + c))*H*W;
        float v = w00*f[i00] + w10*f[i10] + w01*f[i01] + w11*f[i11];
        fused[(size_t)m*576 + 256 + c*64 + ij] = f2bf(v);
    }
    fused[(size_t)m*576 + 512 + ij] = f2bf(gc[b*64 + ij]);
}

extern "C" void kernel_launch(void* const* d_in, const int* in_sizes, int n_in,
                              void* d_out, int out_size, void* d_ws, size_t ws_size,
                              hipStream_t stream) {
    const float* points = (const float*)d_in[0];
    const float* images = (const float*)d_in[1];
    const float* pw1 = (const float*)d_in[2];  const float* pb1 = (const float*)d_in[3];
    const float* pw2 = (const float*)d_in[4];  const float* pb2 = (const float*)d_in[5];
    const float* pw3 = (const float*)d_in[6];  const float* pb3 = (const float*)d_in[7];
    const float* gw1 = (const float*)d_in[8];  const float* gb1 = (const float*)d_in[9];
    const float* gw2 = (const float*)d_in[10]; const float* gb2 = (const float*)d_in[11];
    const float* gw3 = (const float*)d_in[12]; const float* gb3 = (const float*)d_in[13];
    const float* gw4 = (const float*)d_in[14]; const float* gb4 = (const float*)d_in[15];
    const float* gw5 = (const float*)d_in[16]; const float* gb5 = (const float*)d_in[17];
    const float* lw1 = (const float*)d_in[18]; const float* lb1 = (const float*)d_in[19];
    const float* lw2 = (const float*)d_in[20]; const float* lb2 = (const float*)d_in[21];
    const float* hw1 = (const float*)d_in[22]; const float* hb1 = (const float*)d_in[23];
    const float* hw2 = (const float*)d_in[24]; const float* hb2 = (const float*)d_in[25];
    float* out = (float*)d_out;

    // ---- workspace layout ----
    char* base = (char*)d_ws;
    unsigned short* fused_b = (unsigned short*)base;                       // M*576 bf16
    unsigned short* hid_b   = fused_b + (size_t)M_TOT*576;                 // M*256 bf16
    float* fmap = (float*)(hid_b + (size_t)M_TOT*256);                     // 16*4*56*56
    float* gc   = fmap + (size_t)16*4*56*56;                               // 1024
    unsigned short* blw1 = (unsigned short*)(gc + 1024);                   // 256*64
    unsigned short* blw2 = blw1 + 256*64;                                  // 256*256
    unsigned short* bhw1 = blw2 + 256*256;                                 // 512*576
    // conv temps alias inside the fused region (dead before gemm2 writes fused):
    float* ct = (float*)base;
    float* f1 = ct;
    float* f2 = f1 + (size_t)16*16*112*112;
    float* g1 = f2 + (size_t)16*32*56*56;
    float* g2 = g1 + (size_t)16*4*112*112;
    float* g3 = g2 + (size_t)16*8*56*56;
    float* g4 = g3 + (size_t)16*16*28*28;
    float* g5 = g4 + (size_t)16*32*14*14;

    cvtall_k<<<1472, 256, 0, stream>>>(lw1, lw2, hw1, blw1, blw2, bhw1);
    // plane encoder
    conv_tile_k<3,16,2> <<<dim3(7,7,16), 256, 0, stream>>>(images, pw1, pb1, f1,   224,224, 112,112);
    conv_tile_k<16,32,2><<<dim3(4,4,16), 256, 0, stream>>>(f1,     pw2, pb2, f2,   112,112,  56, 56);
    conv_tile_k<32,4,1> <<<dim3(4,4,16), 256, 0, stream>>>(f2,     pw3, pb3, fmap,  56, 56,  56, 56);
    // global encoder
    conv_tile_k<3,4,2>  <<<dim3(7,7,16), 256, 0, stream>>>(images, gw1, gb1, g1,   224,224, 112,112);
    conv_tile_k<4,8,2>  <<<dim3(4,4,16), 256, 0, stream>>>(g1,     gw2, gb2, g2,   112,112,  56, 56);
    conv_tile_k<8,16,2> <<<dim3(2,2,16), 256, 0, stream>>>(g2,     gw3, gb3, g3,    56, 56,  28, 28);
    conv3x3_k<<<dim3(1,1,16*32), dim3(16,16), 0, stream>>>(g3, gw4, gb4, g4, 16, 28, 28, 32, 14, 14, 2);
    conv3x3_k<<<dim3(1,1,16*64), dim3(16,16), 0, stream>>>(g4, gw5, gb5, g5, 32, 14, 14, 64,  7,  7, 2);
    avgpool7_k<<<4, 256, 0, stream>>>(g5, gc);
    // point branch: embed+mlp1 fused, then mlp2 (full-N blocks)
    mlp1_k<<<M_TOT/64, 256, 0, stream>>>(points, blw1, lb1, hid_b);
    gemm_fn_k<4><<<M_TOT/64, 256, 0, stream>>>(hid_b, 256, blw2, 256, lb2, fused_b, 576, 256, 0);
    // patches + gc broadcast
    fill_k<<<(M_TOT*64)/256, 256, 0, stream>>>(fmap, points, gc, fused_b);
    // head: full-N gemm(576->512)+gelu+dot(512->1), direct store
    gemm_hd_k<<<M_TOT/64, 256, 0, stream>>>(fused_b, 576, bhw1, 576, hb1, hw2, hb2, out, 576);
}

// Round 7
// 490.647 us; speedup vs baseline: 2.4866x; 1.0290x over previous
//
#include <hip/hip_runtime.h>
#include <math.h>

#define BB 16
#define NN 4096
#define M_TOT (BB*NN)   // 65536 points
#define TBK 32

typedef __attribute__((ext_vector_type(8))) short s8v;   // 8 bf16 = 4 VGPRs
typedef __attribute__((ext_vector_type(4))) float f4v;

// exact tanh-GELU via sigmoid identity: 0.5x(1+tanh(z)) = x * sigmoid(2z)
__device__ __forceinline__ float gelu_t(float x){
    float u = 1.5957691216057308f * x * (1.0f + 0.044715f*x*x);
    return x / (1.0f + __expf(-u));
}

__device__ __forceinline__ unsigned short f2bf(float f){
    unsigned int u = __float_as_uint(f);
    u += 0x7fffu + ((u >> 16) & 1u);
    return (unsigned short)(u >> 16);
}

#define GLL(src, dst) __builtin_amdgcn_global_load_lds( \
    (const __attribute__((address_space(1))) void*)(src), \
    (__attribute__((address_space(3))) void*)(dst), 16, 0, 0)

// ---------------- LDS-tiled conv 3x3, pad 1, GELU epilogue ----------------
template<int CIN, int COUT, int STRIDE>
__global__ __launch_bounds__(256) void conv_tile_k(
    const float* __restrict__ in, const float* __restrict__ w,
    const float* __restrict__ bias, float* __restrict__ out,
    int Hin, int Win, int Hout, int Wout)
{
    constexpr int IW = 15*STRIDE + 3;
    constexpr int IH = IW;
    __shared__ float tile[IH][IW + 1];
    int tid = threadIdx.x;
    int tx = tid & 15, ty = tid >> 4;
    int b = blockIdx.z;
    int wo = blockIdx.x*16 + tx;
    int ho = blockIdx.y*16 + ty;
    int win0 = blockIdx.x*16*STRIDE - 1;
    int hin0 = blockIdx.y*16*STRIDE - 1;
    bool valid = (wo < Wout) && (ho < Hout);

    float acc[COUT];
    #pragma unroll
    for (int co = 0; co < COUT; ++co) acc[co] = bias[co];

    const float* ib = in + (size_t)(b*CIN)*Hin*Win;
    for (int ci = 0; ci < CIN; ++ci) {
        __syncthreads();
        const float* ic = ib + (size_t)ci*Hin*Win;
        for (int idx = tid; idx < IH*IW; idx += 256) {
            int r = idx / IW, c = idx - r*IW;
            int hi = hin0 + r, wi = win0 + c;
            float v = 0.f;
            if ((unsigned)hi < (unsigned)Hin && (unsigned)wi < (unsigned)Win)
                v = ic[hi*Win + wi];
            tile[r][c] = v;
        }
        __syncthreads();
        float vv[9];
        #pragma unroll
        for (int kh = 0; kh < 3; ++kh)
            #pragma unroll
            for (int kw = 0; kw < 3; ++kw)
                vv[kh*3+kw] = tile[ty*STRIDE + kh][tx*STRIDE + kw];
        const float* wc = w + ci*9;
        #pragma unroll
        for (int co = 0; co < COUT; ++co) {
            const float* wp = wc + co*CIN*9;
            #pragma unroll
            for (int k = 0; k < 9; ++k)
                acc[co] = fmaf(vv[k], wp[k], acc[co]);
        }
    }
    if (valid) {
        size_t obase = ((size_t)b*COUT)*Hout*Wout + (size_t)ho*Wout + wo;
        #pragma unroll
        for (int co = 0; co < COUT; ++co)
            out[obase + (size_t)co*Hout*Wout] = gelu_t(acc[co]);
    }
}

// ---------------- dual conv: plane-conv1 (16ch) + global-conv1 (4ch), shared input ----------------
__global__ __launch_bounds__(256) void conv_dual_k(
    const float* __restrict__ in,
    const float* __restrict__ wA, const float* __restrict__ bA,
    const float* __restrict__ wB, const float* __restrict__ bB,
    float* __restrict__ outA, float* __restrict__ outB)
{
    // CIN=3, STRIDE=2, Hin=Win=224, Hout=Wout=112
    constexpr int IW = 33, IH = 33;
    const int Hin = 224, Win = 224, Hout = 112, Wout = 112;
    __shared__ float tile[IH][IW + 1];
    int tid = threadIdx.x;
    int tx = tid & 15, ty = tid >> 4;
    int b = blockIdx.z;
    int wo = blockIdx.x*16 + tx;
    int ho = blockIdx.y*16 + ty;
    int win0 = blockIdx.x*32 - 1;
    int hin0 = blockIdx.y*32 - 1;

    float accA[16], accB[4];
    #pragma unroll
    for (int co = 0; co < 16; ++co) accA[co] = bA[co];
    #pragma unroll
    for (int co = 0; co < 4; ++co) accB[co] = bB[co];

    const float* ib = in + (size_t)(b*3)*Hin*Win;
    for (int ci = 0; ci < 3; ++ci) {
        __syncthreads();
        const float* ic = ib + (size_t)ci*Hin*Win;
        for (int idx = tid; idx < IH*IW; idx += 256) {
            int r = idx / IW, c = idx - r*IW;
            int hi = hin0 + r, wi = win0 + c;
            float v = 0.f;
            if ((unsigned)hi < (unsigned)Hin && (unsigned)wi < (unsigned)Win)
                v = ic[hi*Win + wi];
            tile[r][c] = v;
        }
        __syncthreads();
        float vv[9];
        #pragma unroll
        for (int kh = 0; kh < 3; ++kh)
            #pragma unroll
            for (int kw = 0; kw < 3; ++kw)
                vv[kh*3+kw] = tile[ty*2 + kh][tx*2 + kw];
        #pragma unroll
        for (int co = 0; co < 16; ++co) {
            const float* wp = wA + co*27 + ci*9;
            #pragma unroll
            for (int k = 0; k < 9; ++k) accA[co] = fmaf(vv[k], wp[k], accA[co]);
        }
        #pragma unroll
        for (int co = 0; co < 4; ++co) {
            const float* wp = wB + co*27 + ci*9;
            #pragma unroll
            for (int k = 0; k < 9; ++k) accB[co] = fmaf(vv[k], wp[k], accB[co]);
        }
    }
    size_t px = (size_t)ho*Wout + wo;
    #pragma unroll
    for (int co = 0; co < 16; ++co)
        outA[((size_t)(b*16 + co))*Hout*Wout + px] = gelu_t(accA[co]);
    #pragma unroll
    for (int co = 0; co < 4; ++co)
        outB[((size_t)(b*4 + co))*Hout*Wout + px] = gelu_t(accB[co]);
}

// ---------------- fallback scalar conv (tiny tail maps) ----------------
__global__ void conv3x3_k(const float* __restrict__ in, const float* __restrict__ w,
                          const float* __restrict__ bias, float* __restrict__ out,
                          int Cin, int Hin, int Win, int Cout, int Hout, int Wout, int stride)
{
    int wo = blockIdx.x*16 + threadIdx.x;
    int ho = blockIdx.y*16 + threadIdx.y;
    int bc = blockIdx.z;
    int co = bc % Cout, b = bc / Cout;
    if (wo >= Wout || ho >= Hout) return;
    const float* wp = w + co*Cin*9;
    const float* ip = in + (size_t)(b*Cin)*Hin*Win;
    float acc = bias[co];
    int hbase = ho*stride - 1, wbase = wo*stride - 1;
    for (int ci = 0; ci < Cin; ++ci) {
        const float* ic = ip + (size_t)ci*Hin*Win;
        const float* wc = wp + ci*9;
        #pragma unroll
        for (int kh = 0; kh < 3; ++kh) {
            int hi = hbase + kh;
            if ((unsigned)hi >= (unsigned)Hin) continue;
            #pragma unroll
            for (int kw = 0; kw < 3; ++kw) {
                int wi = wbase + kw;
                if ((unsigned)wi >= (unsigned)Win) continue;
                acc = fmaf(ic[hi*Win + wi], wc[kh*3+kw], acc);
            }
        }
    }
    out[(((size_t)b*Cout + co)*Hout + ho)*Wout + wo] = gelu_t(acc);
}

// ---------------- global avg pool 7x7 ----------------
__global__ void avgpool7_k(const float* __restrict__ in, float* __restrict__ out){
    int i = blockIdx.x*blockDim.x + threadIdx.x;
    if (i >= BB*64) return;
    const float* p = in + (size_t)i*49;
    float s = 0.f;
    #pragma unroll
    for (int k = 0; k < 49; ++k) s += p[k];
    out[i] = s * (1.0f/49.0f);
}

// ---------------- fused weight conversions (lw1 pad + lw2 + hw1) ----------------
__global__ void cvtall_k(const float* __restrict__ lw1, const float* __restrict__ lw2,
                         const float* __restrict__ hw1, unsigned short* __restrict__ blw1,
                         unsigned short* __restrict__ blw2, unsigned short* __restrict__ bhw1){
    int i = blockIdx.x*blockDim.x + threadIdx.x;
    if (i < 256*64) {
        int r = i >> 6, c = i & 63;
        blw1[i] = (c < 48) ? f2bf(lw1[r*48 + c]) : 0;
        return;
    }
    i -= 256*64;
    if (i < 256*256) { blw2[i] = f2bf(lw2[i]); return; }
    i -= 256*256;
    if (i < 512*576) bhw1[i] = f2bf(hw1[i]);
}

// ---------------- mlp1 fused with embedding: points -> gelu(pe@lw1^T+b) ----------------
__global__ __launch_bounds__(256) void mlp1_k(
    const float* __restrict__ points, const unsigned short* __restrict__ W,
    const float* __restrict__ bias, unsigned short* __restrict__ C)
{
    __shared__ unsigned short As[64*64];
    __shared__ unsigned short Bs[256*64];
    int tid = threadIdx.x;
    int wv = tid >> 6, lane = tid & 63;
    int q = lane >> 4, lr = lane & 15;
    int nqw = wv*64;

    #pragma unroll
    for (int r = 0; r < 8; ++r) {
        int c = r*256 + tid;
        int row = c >> 3, pp = c & 7, pl = pp ^ (row & 7);
        GLL(W + row*64 + pl*8, Bs + c*8);
    }
    #pragma unroll
    for (int r = 0; r < 2; ++r) {
        int c = r*256 + tid;
        int row = c >> 3, pp = c & 7, pl = pp ^ (row & 7);
        int m = blockIdx.x*64 + row;
        float px = points[m*2], py = points[m*2+1];
        union { s8v v; unsigned short u[8]; } pk;
        #pragma unroll
        for (int j = 0; j < 8; ++j) {
            int k = pl*8 + j;
            unsigned short val = 0;
            if (k < 48) {
                int i = k >> 2, rr = k & 3;
                float f = (float)(1 << i);
                float p = (rr & 1) ? py : px;
                float s = f * p;
                val = f2bf((rr < 2) ? __sinf(s) : __cosf(s));
            }
            pk.u[j] = val;
        }
        *(s8v*)(As + c*8) = pk.v;
    }
    __syncthreads();

    f4v acc[4][4];
    #pragma unroll
    for (int i = 0; i < 4; ++i)
        #pragma unroll
        for (int j = 0; j < 4; ++j) acc[i][j] = (f4v){0.f,0.f,0.f,0.f};

    #pragma unroll
    for (int kb = 0; kb < 2; ++kb) {
        s8v a[4], b[4];
        #pragma unroll
        for (int t = 0; t < 4; ++t) {
            int row = t*16 + lr;
            int pp = (kb*4 + q) ^ (row & 7);
            a[t] = *(const s8v*)(As + row*64 + pp*8);
        }
        #pragma unroll
        for (int t = 0; t < 4; ++t) {
            int row = nqw + t*16 + lr;
            int pp = (kb*4 + q) ^ (row & 7);
            b[t] = *(const s8v*)(Bs + row*64 + pp*8);
        }
        #pragma unroll
        for (int mt = 0; mt < 4; ++mt)
            #pragma unroll
            for (int nt = 0; nt < 4; ++nt)
                acc[mt][nt] = __builtin_amdgcn_mfma_f32_16x16x32_bf16(a[mt], b[nt], acc[mt][nt], 0, 0, 0);
    }
    #pragma unroll
    for (int mt = 0; mt < 4; ++mt)
        #pragma unroll
        for (int r4 = 0; r4 < 4; ++r4) {
            size_t m = (size_t)blockIdx.x*64 + mt*16 + q*4 + r4;
            #pragma unroll
            for (int nt = 0; nt < 4; ++nt) {
                int n = nqw + nt*16 + lr;
                C[m*256 + n] = f2bf(gelu_t(acc[mt][nt][r4] + bias[n]));
            }
        }
}

// ================= mlp2 (hid@lw2^T+b -> fused[:,0:256]) + patch/gc fill =================
// 512 threads, M-strip 256, N=256, K=256. Wave (ms=wv>>1, nh=wv&1): 64m x 128n.
__global__ __launch_bounds__(512) void mlp2_k(
    const unsigned short* __restrict__ A,      // hid [M][256]
    const unsigned short* __restrict__ W,      // blw2 [256][256]
    const float* __restrict__ bias,
    unsigned short* __restrict__ C,            // fused [M][576]
    const float* __restrict__ fmap, const float* __restrict__ points,
    const float* __restrict__ gc)
{
    __shared__ unsigned short As[256*TBK];
    __shared__ unsigned short Bs[256*TBK];
    int tid = threadIdx.x;
    int wv = tid >> 6, lane = tid & 63;
    int q = lane >> 4, lr = lane & 15;
    int sw = q ^ ((lr >> 1) & 3);
    int ms = wv >> 1, nb = (wv & 1) * 128;
    size_t m0 = (size_t)blockIdx.x * 256;
    const unsigned short* Ab = A + m0*256;

    const unsigned short* srcA[2]; unsigned short* dstA[2];
    const unsigned short* srcB[2]; unsigned short* dstB[2];
    #pragma unroll
    for (int r = 0; r < 2; ++r) {
        int f = r*512 + tid;
        int rr = f >> 2, ll = (f & 3) ^ ((rr >> 1) & 3);
        srcA[r] = Ab + (size_t)rr*256 + ll*8;
        dstA[r] = As + f*8;
        srcB[r] = W + (size_t)rr*256 + ll*8;
        dstB[r] = Bs + f*8;
    }

    f4v acc[4][8];
    #pragma unroll
    for (int i = 0; i < 4; ++i)
        #pragma unroll
        for (int j = 0; j < 8; ++j) acc[i][j] = (f4v){0.f,0.f,0.f,0.f};

    for (int k0 = 0; k0 < 256; k0 += TBK) {
        #pragma unroll
        for (int r = 0; r < 2; ++r) {
            GLL(srcA[r], dstA[r]); srcA[r] += TBK;
            GLL(srcB[r], dstB[r]); srcB[r] += TBK;
        }
        __syncthreads();
        s8v a[4], b[8];
        #pragma unroll
        for (int t = 0; t < 4; ++t)
            a[t] = *(const s8v*)(As + (ms*64 + t*16 + lr)*TBK + sw*8);
        #pragma unroll
        for (int t = 0; t < 8; ++t)
            b[t] = *(const s8v*)(Bs + (nb + t*16 + lr)*TBK + sw*8);
        #pragma unroll
        for (int mt = 0; mt < 4; ++mt)
            #pragma unroll
            for (int nt = 0; nt < 8; ++nt)
                acc[mt][nt] = __builtin_amdgcn_mfma_f32_16x16x32_bf16(a[mt], b[nt], acc[mt][nt], 0, 0, 0);
        __syncthreads();
    }
    #pragma unroll
    for (int mt = 0; mt < 4; ++mt)
        #pragma unroll
        for (int r4 = 0; r4 < 4; ++r4) {
            size_t m = m0 + ms*64 + mt*16 + q*4 + r4;
            #pragma unroll
            for (int nt = 0; nt < 8; ++nt) {
                int n = nb + nt*16 + lr;
                C[m*576 + n] = f2bf(acc[mt][nt][r4] + bias[n]);
            }
        }
    // ---- fused fill: patches (cols 256..511) + gc (512..575) for these 256 rows ----
    const int W56 = 56, H56 = 56;
    #pragma unroll 1
    for (int it = 0; it < 32; ++it) {
        int task = it*512 + tid;
        int ml = task >> 6, ij = task & 63;
        size_t m = m0 + ml;
        int i = ij >> 3, j = ij & 7;
        int b = (int)(m >> 12);
        float px = points[m*2], py = points[m*2+1];
        float cx = px*2.f - 1.f, cy = py*2.f - 1.f;
        const float step = 2.0f/55.0f;
        float gx = cx + ((float)i - 3.5f)*step;
        float gy = cy + ((float)j - 3.5f)*step;
        float ix = (gx + 1.f)*0.5f*55.f;
        float iy = (gy + 1.f)*0.5f*55.f;
        float x0f = floorf(ix), y0f = floorf(iy);
        int x0 = (int)x0f, y0 = (int)y0f;
        int x1 = x0 + 1,  y1 = y0 + 1;
        float wx1 = ix - x0f, wx0 = 1.f - wx1;
        float wy1 = iy - y0f, wy0 = 1.f - wy1;
        float v00 = ((x0>=0)&&(x0<W56)&&(y0>=0)&&(y0<H56)) ? 1.f : 0.f;
        float v10 = ((x1>=0)&&(x1<W56)&&(y0>=0)&&(y0<H56)) ? 1.f : 0.f;
        float v01 = ((x0>=0)&&(x0<W56)&&(y1>=0)&&(y1<H56)) ? 1.f : 0.f;
        float v11 = ((x1>=0)&&(x1<W56)&&(y1>=0)&&(y1<H56)) ? 1.f : 0.f;
        float w00 = wx0*wy0*v00, w10 = wx1*wy0*v10, w01 = wx0*wy1*v01, w11 = wx1*wy1*v11;
        int cx0 = min(max(x0,0),W56-1), cx1 = min(max(x1,0),W56-1);
        int cy0 = min(max(y0,0),H56-1), cy1 = min(max(y1,0),H56-1);
        int i00 = cy0*W56 + cx0, i10 = cy0*W56 + cx1, i01 = cy1*W56 + cx0, i11 = cy1*W56 + cx1;
        #pragma unroll
        for (int c = 0; c < 4; ++c) {
            const float* f = fmap + ((size_t)(b*4 + c))*H56*W56;
            float v = w00*f[i00] + w10*f[i10] + w01*f[i01] + w11*f[i11];
            C[m*576 + 256 + c*64 + ij] = f2bf(v);
        }
        C[m*576 + 512 + ij] = f2bf(gc[b*64 + ij]);
    }
}

// ================= head: gemm(576->512)+gelu + dot(512->1), direct store =================
// 512 threads, M-strip 128, N=512 full. Wave (ms=wv>>2, nq=wv&3): 64m x 128n.
__global__ __launch_bounds__(512) void gemm_hd_k(
    const unsigned short* __restrict__ A, int lda,
    const unsigned short* __restrict__ W, int ldw,
    const float* __restrict__ bias, const float* __restrict__ w2,
    const float* __restrict__ b2, float* __restrict__ out, int K)
{
    __shared__ unsigned short As[128*TBK];   // 8 KB
    __shared__ unsigned short Bs[512*TBK];   // 32 KB
    __shared__ float red[8*64];
    int tid = threadIdx.x;
    int wv = tid >> 6, lane = tid & 63;
    int q = lane >> 4, lr = lane & 15;
    int sw = q ^ ((lr >> 1) & 3);
    int ms = wv >> 2, nb = (wv & 3) * 128;
    const unsigned short* Ab = A + (size_t)blockIdx.x*128*lda;

    int rA = tid >> 2;
    int lA = (tid & 3) ^ ((rA >> 1) & 3);
    const unsigned short* srcA = Ab + (size_t)rA*lda + lA*8;
    unsigned short* dstA = As + tid*8;
    const unsigned short* srcB[4]; unsigned short* dstB[4];
    #pragma unroll
    for (int r = 0; r < 4; ++r) {
        int f = r*512 + tid;
        int rr = f >> 2, ll = (f & 3) ^ ((rr >> 1) & 3);
        srcB[r] = W + (size_t)rr*ldw + ll*8;
        dstB[r] = Bs + f*8;
    }

    f4v acc[4][8];
    #pragma unroll
    for (int i = 0; i < 4; ++i)
        #pragma unroll
        for (int j = 0; j < 8; ++j) acc[i][j] = (f4v){0.f,0.f,0.f,0.f};

    for (int k0 = 0; k0 < K; k0 += TBK) {
        GLL(srcA, dstA); srcA += TBK;
        #pragma unroll
        for (int r = 0; r < 4; ++r) { GLL(srcB[r], dstB[r]); srcB[r] += TBK; }
        __syncthreads();
        s8v a[4], b[8];
        #pragma unroll
        for (int t = 0; t < 4; ++t)
            a[t] = *(const s8v*)(As + (ms*64 + t*16 + lr)*TBK + sw*8);
        #pragma unroll
        for (int t = 0; t < 8; ++t)
            b[t] = *(const s8v*)(Bs + (nb + t*16 + lr)*TBK + sw*8);
        #pragma unroll
        for (int mt = 0; mt < 4; ++mt)
            #pragma unroll
            for (int nt = 0; nt < 8; ++nt)
                acc[mt][nt] = __builtin_amdgcn_mfma_f32_16x16x32_bf16(a[mt], b[nt], acc[mt][nt], 0, 0, 0);
        __syncthreads();
    }
    float bv[8], w2v[8];
    #pragma unroll
    for (int nt = 0; nt < 8; ++nt) {
        int n = nb + nt*16 + lr;
        bv[nt] = bias[n];
        w2v[nt] = w2[n];
    }
    #pragma unroll
    for (int mt = 0; mt < 4; ++mt)
        #pragma unroll
        for (int r4 = 0; r4 < 4; ++r4) {
            int ml = mt*16 + q*4 + r4;
            float s = 0.f;
            #pragma unroll
            for (int nt = 0; nt < 8; ++nt)
                s += gelu_t(acc[mt][nt][r4] + bv[nt]) * w2v[nt];
            #pragma unroll
            for (int off = 8; off > 0; off >>= 1) s += __shfl_down(s, off, 16);
            if (lr == 0) red[wv*64 + ml] = s;
        }
    __syncthreads();
    if (tid < 128) {
        int msf = tid >> 6, ml = tid & 63;
        float t = red[(msf*4+0)*64 + ml] + red[(msf*4+1)*64 + ml]
                + red[(msf*4+2)*64 + ml] + red[(msf*4+3)*64 + ml];
        out[blockIdx.x*128 + tid] = t + b2[0];
    }
}

extern "C" void kernel_launch(void* const* d_in, const int* in_sizes, int n_in,
                              void* d_out, int out_size, void* d_ws, size_t ws_size,
                              hipStream_t stream) {
    const float* points = (const float*)d_in[0];
    const float* images = (const float*)d_in[1];
    const float* pw1 = (const float*)d_in[2];  const float* pb1 = (const float*)d_in[3];
    const float* pw2 = (const float*)d_in[4];  const float* pb2 = (const float*)d_in[5];
    const float* pw3 = (const float*)d_in[6];  const float* pb3 = (const float*)d_in[7];
    const float* gw1 = (const float*)d_in[8];  const float* gb1 = (const float*)d_in[9];
    const float* gw2 = (const float*)d_in[10]; const float* gb2 = (const float*)d_in[11];
    const float* gw3 = (const float*)d_in[12]; const float* gb3 = (const float*)d_in[13];
    const float* gw4 = (const float*)d_in[14]; const float* gb4 = (const float*)d_in[15];
    const float* gw5 = (const float*)d_in[16]; const float* gb5 = (const float*)d_in[17];
    const float* lw1 = (const float*)d_in[18]; const float* lb1 = (const float*)d_in[19];
    const float* lw2 = (const float*)d_in[20]; const float* lb2 = (const float*)d_in[21];
    const float* hw1 = (const float*)d_in[22]; const float* hb1 = (const float*)d_in[23];
    const float* hw2 = (const float*)d_in[24]; const float* hb2 = (const float*)d_in[25];
    float* out = (float*)d_out;

    // ---- workspace layout ----
    char* base = (char*)d_ws;
    unsigned short* fused_b = (unsigned short*)base;                       // M*576 bf16
    unsigned short* hid_b   = fused_b + (size_t)M_TOT*576;                 // M*256 bf16
    float* fmap = (float*)(hid_b + (size_t)M_TOT*256);                     // 16*4*56*56
    float* gc   = fmap + (size_t)16*4*56*56;                               // 1024
    unsigned short* blw1 = (unsigned short*)(gc + 1024);                   // 256*64
    unsigned short* blw2 = blw1 + 256*64;                                  // 256*256
    unsigned short* bhw1 = blw2 + 256*256;                                 // 512*576
    // conv temps alias inside the fused region (dead before mlp2 writes fused):
    float* ct = (float*)base;
    float* f1 = ct;
    float* f2 = f1 + (size_t)16*16*112*112;
    float* g1 = f2 + (size_t)16*32*56*56;
    float* g2 = g1 + (size_t)16*4*112*112;
    float* g3 = g2 + (size_t)16*8*56*56;
    float* g4 = g3 + (size_t)16*16*28*28;
    float* g5 = g4 + (size_t)16*32*14*14;

    cvtall_k<<<1472, 256, 0, stream>>>(lw1, lw2, hw1, blw1, blw2, bhw1);
    // conv1 of both encoders fused (shared image read)
    conv_dual_k<<<dim3(7,7,16), 256, 0, stream>>>(images, pw1, pb1, gw1, gb1, f1, g1);
    // plane encoder tail
    conv_tile_k<16,32,2><<<dim3(4,4,16), 256, 0, stream>>>(f1, pw2, pb2, f2,   112,112, 56,56);
    conv_tile_k<32,4,1> <<<dim3(4,4,16), 256, 0, stream>>>(f2, pw3, pb3, fmap,  56, 56, 56,56);
    // global encoder tail
    conv_tile_k<4,8,2>  <<<dim3(4,4,16), 256, 0, stream>>>(g1, gw2, gb2, g2,   112,112, 56,56);
    conv_tile_k<8,16,2> <<<dim3(2,2,16), 256, 0, stream>>>(g2, gw3, gb3, g3,    56, 56, 28,28);
    conv3x3_k<<<dim3(1,1,16*32), dim3(16,16), 0, stream>>>(g3, gw4, gb4, g4, 16, 28, 28, 32, 14, 14, 2);
    conv3x3_k<<<dim3(1,1,16*64), dim3(16,16), 0, stream>>>(g4, gw5, gb5, g5, 32, 14, 14, 64,  7,  7, 2);
    avgpool7_k<<<4, 256, 0, stream>>>(g5, gc);
    // point branch
    mlp1_k<<<M_TOT/64, 256, 0, stream>>>(points, blw1, lb1, hid_b);
    // mlp2 + patch/gc fill (fused), M-strip 256
    mlp2_k<<<M_TOT/256, 512, 0, stream>>>(hid_b, blw2, lb2, fused_b, fmap, points, gc);
    // head, M-strip 128
    gemm_hd_k<<<M_TOT/128, 512, 0, stream>>>(fused_b, 576, bhw1, 576, hb1, hw2, hb2, out, 576);
}

// Round 9
// 467.566 us; speedup vs baseline: 2.6093x; 1.0494x over previous
//
#include <hip/hip_runtime.h>
#include <math.h>

#define BB 16
#define NN 4096
#define M_TOT (BB*NN)   // 65536 points
#define TBK 32

typedef __attribute__((ext_vector_type(8))) short s8v;   // 8 bf16 = 4 VGPRs
typedef __attribute__((ext_vector_type(4))) float f4v;

// exact tanh-GELU via sigmoid identity: 0.5x(1+tanh(z)) = x * sigmoid(2z)
__device__ __forceinline__ float gelu_t(float x){
    float u = 1.5957691216057308f * x * (1.0f + 0.044715f*x*x);
    return x / (1.0f + __expf(-u));
}

__device__ __forceinline__ unsigned short f2bf(float f){
    unsigned int u = __float_as_uint(f);
    u += 0x7fffu + ((u >> 16) & 1u);
    return (unsigned short)(u >> 16);
}

#define GLL(src, dst) __builtin_amdgcn_global_load_lds( \
    (const __attribute__((address_space(1))) void*)(src), \
    (__attribute__((address_space(3))) void*)(dst), 16, 0, 0)

// ---------------- LDS-tiled conv 3x3, pad 1, GELU epilogue ----------------
template<int CIN, int COUT, int STRIDE>
__global__ __launch_bounds__(256) void conv_tile_k(
    const float* __restrict__ in, const float* __restrict__ w,
    const float* __restrict__ bias, float* __restrict__ out,
    int Hin, int Win, int Hout, int Wout)
{
    constexpr int IW = 15*STRIDE + 3;
    constexpr int IH = IW;
    __shared__ float tile[IH][IW + 1];
    int tid = threadIdx.x;
    int tx = tid & 15, ty = tid >> 4;
    int b = blockIdx.z;
    int wo = blockIdx.x*16 + tx;
    int ho = blockIdx.y*16 + ty;
    int win0 = blockIdx.x*16*STRIDE - 1;
    int hin0 = blockIdx.y*16*STRIDE - 1;
    bool valid = (wo < Wout) && (ho < Hout);

    float acc[COUT];
    #pragma unroll
    for (int co = 0; co < COUT; ++co) acc[co] = bias[co];

    const float* ib = in + (size_t)(b*CIN)*Hin*Win;
    for (int ci = 0; ci < CIN; ++ci) {
        __syncthreads();
        const float* ic = ib + (size_t)ci*Hin*Win;
        for (int idx = tid; idx < IH*IW; idx += 256) {
            int r = idx / IW, c = idx - r*IW;
            int hi = hin0 + r, wi = win0 + c;
            float v = 0.f;
            if ((unsigned)hi < (unsigned)Hin && (unsigned)wi < (unsigned)Win)
                v = ic[hi*Win + wi];
            tile[r][c] = v;
        }
        __syncthreads();
        float vv[9];
        #pragma unroll
        for (int kh = 0; kh < 3; ++kh)
            #pragma unroll
            for (int kw = 0; kw < 3; ++kw)
                vv[kh*3+kw] = tile[ty*STRIDE + kh][tx*STRIDE + kw];
        const float* wc = w + ci*9;
        #pragma unroll
        for (int co = 0; co < COUT; ++co) {
            const float* wp = wc + co*CIN*9;
            #pragma unroll
            for (int k = 0; k < 9; ++k)
                acc[co] = fmaf(vv[k], wp[k], acc[co]);
        }
    }
    if (valid) {
        size_t obase = ((size_t)b*COUT)*Hout*Wout + (size_t)ho*Wout + wo;
        #pragma unroll
        for (int co = 0; co < COUT; ++co)
            out[obase + (size_t)co*Hout*Wout] = gelu_t(acc[co]);
    }
}

// ---------------- conv_p3: 32 -> 4 channels, stride 1, 56x56, NHWC float4 out ----------------
__global__ __launch_bounds__(256) void conv_p3_k(
    const float* __restrict__ in, const float* __restrict__ w,
    const float* __restrict__ bias, float4* __restrict__ out)
{
    __shared__ float tile[18][19];
    int tid = threadIdx.x;
    int tx = tid & 15, ty = tid >> 4;
    int b = blockIdx.z;
    int wo = blockIdx.x*16 + tx;
    int ho = blockIdx.y*16 + ty;
    int win0 = blockIdx.x*16 - 1;
    int hin0 = blockIdx.y*16 - 1;
    bool valid = (ho < 56) && (wo < 56);   // <-- FIX: 4x4 tiles of 16 cover 64>56

    float acc[4];
    #pragma unroll
    for (int co = 0; co < 4; ++co) acc[co] = bias[co];

    const float* ib = in + (size_t)(b*32)*3136;
    for (int ci = 0; ci < 32; ++ci) {
        __syncthreads();
        const float* ic = ib + (size_t)ci*3136;
        for (int idx = tid; idx < 18*18; idx += 256) {
            int r = idx / 18, c = idx - r*18;
            int hi = hin0 + r, wi = win0 + c;
            float v = 0.f;
            if ((unsigned)hi < 56u && (unsigned)wi < 56u)
                v = ic[hi*56 + wi];
            tile[r][c] = v;
        }
        __syncthreads();
        float vv[9];
        #pragma unroll
        for (int kh = 0; kh < 3; ++kh)
            #pragma unroll
            for (int kw = 0; kw < 3; ++kw)
                vv[kh*3+kw] = tile[ty + kh][tx + kw];
        #pragma unroll
        for (int co = 0; co < 4; ++co) {
            const float* wp = w + co*288 + ci*9;
            #pragma unroll
            for (int k = 0; k < 9; ++k)
                acc[co] = fmaf(vv[k], wp[k], acc[co]);
        }
    }
    if (valid) {
        float4 o;
        o.x = gelu_t(acc[0]); o.y = gelu_t(acc[1]);
        o.z = gelu_t(acc[2]); o.w = gelu_t(acc[3]);
        out[(size_t)b*3136 + (size_t)ho*56 + wo] = o;
    }
}

// ---------------- dual conv: plane-conv1 (16ch) + global-conv1 (4ch), shared input ----------------
__global__ __launch_bounds__(256) void conv_dual_k(
    const float* __restrict__ in,
    const float* __restrict__ wA, const float* __restrict__ bA,
    const float* __restrict__ wB, const float* __restrict__ bB,
    float* __restrict__ outA, float* __restrict__ outB)
{
    constexpr int IW = 33, IH = 33;
    const int Hin = 224, Win = 224, Hout = 112, Wout = 112;
    __shared__ float tile[IH][IW + 1];
    int tid = threadIdx.x;
    int tx = tid & 15, ty = tid >> 4;
    int b = blockIdx.z;
    int wo = blockIdx.x*16 + tx;
    int ho = blockIdx.y*16 + ty;
    int win0 = blockIdx.x*32 - 1;
    int hin0 = blockIdx.y*32 - 1;

    float accA[16], accB[4];
    #pragma unroll
    for (int co = 0; co < 16; ++co) accA[co] = bA[co];
    #pragma unroll
    for (int co = 0; co < 4; ++co) accB[co] = bB[co];

    const float* ib = in + (size_t)(b*3)*Hin*Win;
    for (int ci = 0; ci < 3; ++ci) {
        __syncthreads();
        const float* ic = ib + (size_t)ci*Hin*Win;
        for (int idx = tid; idx < IH*IW; idx += 256) {
            int r = idx / IW, c = idx - r*IW;
            int hi = hin0 + r, wi = win0 + c;
            float v = 0.f;
            if ((unsigned)hi < (unsigned)Hin && (unsigned)wi < (unsigned)Win)
                v = ic[hi*Win + wi];
            tile[r][c] = v;
        }
        __syncthreads();
        float vv[9];
        #pragma unroll
        for (int kh = 0; kh < 3; ++kh)
            #pragma unroll
            for (int kw = 0; kw < 3; ++kw)
                vv[kh*3+kw] = tile[ty*2 + kh][tx*2 + kw];
        #pragma unroll
        for (int co = 0; co < 16; ++co) {
            const float* wp = wA + co*27 + ci*9;
            #pragma unroll
            for (int k = 0; k < 9; ++k) accA[co] = fmaf(vv[k], wp[k], accA[co]);
        }
        #pragma unroll
        for (int co = 0; co < 4; ++co) {
            const float* wp = wB + co*27 + ci*9;
            #pragma unroll
            for (int k = 0; k < 9; ++k) accB[co] = fmaf(vv[k], wp[k], accB[co]);
        }
    }
    size_t px = (size_t)ho*Wout + wo;
    #pragma unroll
    for (int co = 0; co < 16; ++co)
        outA[((size_t)(b*16 + co))*Hout*Wout + px] = gelu_t(accA[co]);
    #pragma unroll
    for (int co = 0; co < 4; ++co)
        outB[((size_t)(b*4 + co))*Hout*Wout + px] = gelu_t(accB[co]);
}

// ---------------- fallback scalar conv (tiny tail maps), block-size agnostic ----------------
__global__ void conv3x3_k(const float* __restrict__ in, const float* __restrict__ w,
                          const float* __restrict__ bias, float* __restrict__ out,
                          int Cin, int Hin, int Win, int Cout, int Hout, int Wout, int stride)
{
    int wo = blockIdx.x*blockDim.x + threadIdx.x;
    int ho = blockIdx.y*blockDim.y + threadIdx.y;
    int bc = blockIdx.z;
    int co = bc % Cout, b = bc / Cout;
    if (wo >= Wout || ho >= Hout) return;
    const float* wp = w + co*Cin*9;
    const float* ip = in + (size_t)(b*Cin)*Hin*Win;
    float acc = bias[co];
    int hbase = ho*stride - 1, wbase = wo*stride - 1;
    for (int ci = 0; ci < Cin; ++ci) {
        const float* ic = ip + (size_t)ci*Hin*Win;
        const float* wc = wp + ci*9;
        #pragma unroll
        for (int kh = 0; kh < 3; ++kh) {
            int hi = hbase + kh;
            if ((unsigned)hi >= (unsigned)Hin) continue;
            #pragma unroll
            for (int kw = 0; kw < 3; ++kw) {
                int wi = wbase + kw;
                if ((unsigned)wi >= (unsigned)Win) continue;
                acc = fmaf(ic[hi*Win + wi], wc[kh*3+kw], acc);
            }
        }
    }
    out[(((size_t)b*Cout + co)*Hout + ho)*Wout + wo] = gelu_t(acc);
}

// ---------------- global avg pool 7x7 ----------------
__global__ void avgpool7_k(const float* __restrict__ in, float* __restrict__ out){
    int i = blockIdx.x*blockDim.x + threadIdx.x;
    if (i >= BB*64) return;
    const float* p = in + (size_t)i*49;
    float s = 0.f;
    #pragma unroll
    for (int k = 0; k < 49; ++k) s += p[k];
    out[i] = s * (1.0f/49.0f);
}

// ---------------- fused weight conversions (lw1 pad + lw2 + hw1) ----------------
__global__ void cvtall_k(const float* __restrict__ lw1, const float* __restrict__ lw2,
                         const float* __restrict__ hw1, unsigned short* __restrict__ blw1,
                         unsigned short* __restrict__ blw2, unsigned short* __restrict__ bhw1){
    int i = blockIdx.x*blockDim.x + threadIdx.x;
    if (i < 256*64) {
        int r = i >> 6, c = i & 63;
        blw1[i] = (c < 48) ? f2bf(lw1[r*48 + c]) : 0;
        return;
    }
    i -= 256*64;
    if (i < 256*256) { blw2[i] = f2bf(lw2[i]); return; }
    i -= 256*256;
    if (i < 512*576) bhw1[i] = f2bf(hw1[i]);
}

// ================= mlp12: embed + mlp1 + mlp2 + patch/gc fill, M-strip 128 =================
// 512 threads, 8 waves as (mi = wv>>2 in {0,1}, ni = wv&3): each wave 64m x 64n.
// gemm1: A (positional embedding) computed in registers; B1 (lw1) frag-loaded from L2.
// hid kept in LDS (64 KB, swizzled 32-chunk rows). gemm2: B2 staged per-32k tile.
__global__ __launch_bounds__(512) void mlp12_k(
    const float* __restrict__ points,
    const unsigned short* __restrict__ W1, const float* __restrict__ b1,
    const unsigned short* __restrict__ W2, const float* __restrict__ b2,
    unsigned short* __restrict__ C,
    const float4* __restrict__ fmap4, const float* __restrict__ gc)
{
    __shared__ unsigned short Hd[128*256];   // 64 KB
    __shared__ unsigned short B2[256*TBK];   // 16 KB
    int tid = threadIdx.x;
    int wv = tid >> 6, lane = tid & 63;
    int q = lane >> 4, lr = lane & 15;
    int mi = wv >> 2, ni = wv & 3;
    size_t m0 = (size_t)blockIdx.x * 128;

    // ---- gemm1: hid = gelu(pe @ lw1^T + b1), K=64 (48 real + 16 pad) ----
    f4v acc1[4][4];
    #pragma unroll
    for (int i = 0; i < 4; ++i)
        #pragma unroll
        for (int j = 0; j < 4; ++j) acc1[i][j] = (f4v){0.f,0.f,0.f,0.f};

    #pragma unroll
    for (int kb = 0; kb < 2; ++kb) {
        int seg = kb*4 + q;
        s8v a[4], b[4];
        #pragma unroll
        for (int t = 0; t < 4; ++t) {
            size_t m = m0 + mi*64 + t*16 + lr;
            float px = points[m*2], py = points[m*2+1];
            union { s8v v; unsigned short u[8]; } pk;
            #pragma unroll
            for (int j = 0; j < 8; ++j) {
                int k = seg*8 + j;
                unsigned short val = 0;
                if (k < 48) {
                    int i2 = k >> 2, rr = k & 3;
                    float f = (float)(1 << i2);
                    float p = (rr & 1) ? py : px;
                    float s = f * p;
                    val = f2bf((rr < 2) ? __sinf(s) : __cosf(s));
                }
                pk.u[j] = val;
            }
            a[t] = pk.v;
        }
        #pragma unroll
        for (int t = 0; t < 4; ++t) {
            int n = ni*64 + t*16 + lr;
            b[t] = *(const s8v*)(W1 + n*64 + seg*8);
        }
        #pragma unroll
        for (int mt = 0; mt < 4; ++mt)
            #pragma unroll
            for (int nt = 0; nt < 4; ++nt)
                acc1[mt][nt] = __builtin_amdgcn_mfma_f32_16x16x32_bf16(a[mt], b[nt], acc1[mt][nt], 0, 0, 0);
    }
    // epilogue1: gelu -> Hd (swizzled: phys chunk = (col>>3) ^ (row&7))
    {
        float b1v[4];
        #pragma unroll
        for (int nt = 0; nt < 4; ++nt) b1v[nt] = b1[ni*64 + nt*16 + lr];
        #pragma unroll
        for (int mt = 0; mt < 4; ++mt)
            #pragma unroll
            for (int r4 = 0; r4 < 4; ++r4) {
                int row = mi*64 + mt*16 + q*4 + r4;
                #pragma unroll
                for (int nt = 0; nt < 4; ++nt) {
                    int col = ni*64 + nt*16 + lr;
                    float v = gelu_t(acc1[mt][nt][r4] + b1v[nt]);
                    int p = (col >> 3) ^ (row & 7);
                    Hd[(row*32 + p)*8 + (col & 7)] = f2bf(v);
                }
            }
    }
    __syncthreads();

    // ---- gemm2: pf = hid @ lw2^T + b2 (no act), K=256 ----
    f4v acc2[4][4];
    #pragma unroll
    for (int i = 0; i < 4; ++i)
        #pragma unroll
        for (int j = 0; j < 4; ++j) acc2[i][j] = (f4v){0.f,0.f,0.f,0.f};

    for (int kt = 0; kt < 8; ++kt) {
        #pragma unroll
        for (int r = 0; r < 2; ++r) {
            int f = r*512 + tid;
            int rr = f >> 2, ll = (f & 3) ^ ((f >> 3) & 3);
            GLL(W2 + rr*256 + kt*32 + ll*8, B2 + f*8);
        }
        __syncthreads();
        s8v a[4], b[4];
        int sw = q ^ ((lr >> 1) & 3);
        #pragma unroll
        for (int t = 0; t < 4; ++t) {
            int row = mi*64 + t*16 + lr;
            int p = (kt*4 + q) ^ (row & 7);
            a[t] = *(const s8v*)(Hd + (row*32 + p)*8);
        }
        #pragma unroll
        for (int t = 0; t < 4; ++t) {
            int n = ni*64 + t*16 + lr;
            b[t] = *(const s8v*)(B2 + (n*4 + sw)*8);
        }
        #pragma unroll
        for (int mt = 0; mt < 4; ++mt)
            #pragma unroll
            for (int nt = 0; nt < 4; ++nt)
                acc2[mt][nt] = __builtin_amdgcn_mfma_f32_16x16x32_bf16(a[mt], b[nt], acc2[mt][nt], 0, 0, 0);
        __syncthreads();
    }
    // epilogue2: fused cols 0..255
    {
        float b2v[4];
        #pragma unroll
        for (int nt = 0; nt < 4; ++nt) b2v[nt] = b2[ni*64 + nt*16 + lr];
        #pragma unroll
        for (int mt = 0; mt < 4; ++mt)
            #pragma unroll
            for (int r4 = 0; r4 < 4; ++r4) {
                size_t m = m0 + mi*64 + mt*16 + q*4 + r4;
                #pragma unroll
                for (int nt = 0; nt < 4; ++nt) {
                    int n = ni*64 + nt*16 + lr;
                    C[m*576 + n] = f2bf(acc2[mt][nt][r4] + b2v[nt]);
                }
            }
    }
    // ---- fill: patches (float4 NHWC gathers) + gc for these 128 rows ----
    #pragma unroll 1
    for (int it = 0; it < 16; ++it) {
        int task = it*512 + tid;
        int ml = task >> 6, ij = task & 63;
        size_t m = m0 + ml;
        int i = ij >> 3, j = ij & 7;
        int b = (int)(m >> 12);
        float px = points[m*2], py = points[m*2+1];
        float cx = px*2.f - 1.f, cy = py*2.f - 1.f;
        const float step = 2.0f/55.0f;
        float gx = cx + ((float)i - 3.5f)*step;
        float gy = cy + ((float)j - 3.5f)*step;
        float ix = (gx + 1.f)*0.5f*55.f;
        float iy = (gy + 1.f)*0.5f*55.f;
        float x0f = floorf(ix), y0f = floorf(iy);
        int x0 = (int)x0f, y0 = (int)y0f;
        int x1 = x0 + 1,  y1 = y0 + 1;
        float wx1 = ix - x0f, wx0 = 1.f - wx1;
        float wy1 = iy - y0f, wy0 = 1.f - wy1;
        float v00 = ((x0>=0)&&(x0<56)&&(y0>=0)&&(y0<56)) ? 1.f : 0.f;
        float v10 = ((x1>=0)&&(x1<56)&&(y0>=0)&&(y0<56)) ? 1.f : 0.f;
        float v01 = ((x0>=0)&&(x0<56)&&(y1>=0)&&(y1<56)) ? 1.f : 0.f;
        float v11 = ((x1>=0)&&(x1<56)&&(y1>=0)&&(y1<56)) ? 1.f : 0.f;
        float w00 = wx0*wy0*v00, w10 = wx1*wy0*v10, w01 = wx0*wy1*v01, w11 = wx1*wy1*v11;
        int cx0 = min(max(x0,0),55), cx1 = min(max(x1,0),55);
        int cy0 = min(max(y0,0),55), cy1 = min(max(y1,0),55);
        const float4* fb = fmap4 + (size_t)b*3136;
        float4 f00 = fb[cy0*56 + cx0], f10 = fb[cy0*56 + cx1];
        float4 f01 = fb[cy1*56 + cx0], f11 = fb[cy1*56 + cx1];
        float4 v;
        v.x = w00*f00.x + w10*f10.x + w01*f01.x + w11*f11.x;
        v.y = w00*f00.y + w10*f10.y + w01*f01.y + w11*f11.y;
        v.z = w00*f00.z + w10*f10.z + w01*f01.z + w11*f11.z;
        v.w = w00*f00.w + w10*f10.w + w01*f01.w + w11*f11.w;
        C[m*576 + 256 +   0 + ij] = f2bf(v.x);
        C[m*576 + 256 +  64 + ij] = f2bf(v.y);
        C[m*576 + 256 + 128 + ij] = f2bf(v.z);
        C[m*576 + 256 + 192 + ij] = f2bf(v.w);
        C[m*576 + 512 + ij] = f2bf(gc[b*64 + ij]);
    }
}

// ================= head: gemm(576->512)+gelu + dot(512->1), direct store =================
__global__ __launch_bounds__(512) void gemm_hd_k(
    const unsigned short* __restrict__ A, int lda,
    const unsigned short* __restrict__ W, int ldw,
    const float* __restrict__ bias, const float* __restrict__ w2,
    const float* __restrict__ b2, float* __restrict__ out, int K)
{
    __shared__ unsigned short As[128*TBK];   // 8 KB
    __shared__ unsigned short Bs[512*TBK];   // 32 KB
    __shared__ float red[8*64];
    int tid = threadIdx.x;
    int wv = tid >> 6, lane = tid & 63;
    int q = lane >> 4, lr = lane & 15;
    int sw = q ^ ((lr >> 1) & 3);
    int ms = wv >> 2, nb = (wv & 3) * 128;
    const unsigned short* Ab = A + (size_t)blockIdx.x*128*lda;

    int rA = tid >> 2;
    int lA = (tid & 3) ^ ((rA >> 1) & 3);
    const unsigned short* srcA = Ab + (size_t)rA*lda + lA*8;
    unsigned short* dstA = As + tid*8;
    const unsigned short* srcB[4]; unsigned short* dstB[4];
    #pragma unroll
    for (int r = 0; r < 4; ++r) {
        int f = r*512 + tid;
        int rr = f >> 2, ll = (f & 3) ^ ((rr >> 1) & 3);
        srcB[r] = W + (size_t)rr*ldw + ll*8;
        dstB[r] = Bs + f*8;
    }

    f4v acc[4][8];
    #pragma unroll
    for (int i = 0; i < 4; ++i)
        #pragma unroll
        for (int j = 0; j < 8; ++j) acc[i][j] = (f4v){0.f,0.f,0.f,0.f};

    for (int k0 = 0; k0 < K; k0 += TBK) {
        GLL(srcA, dstA); srcA += TBK;
        #pragma unroll
        for (int r = 0; r < 4; ++r) { GLL(srcB[r], dstB[r]); srcB[r] += TBK; }
        __syncthreads();
        s8v a[4], b[8];
        #pragma unroll
        for (int t = 0; t < 4; ++t)
            a[t] = *(const s8v*)(As + (ms*64 + t*16 + lr)*TBK + sw*8);
        #pragma unroll
        for (int t = 0; t < 8; ++t)
            b[t] = *(const s8v*)(Bs + (nb + t*16 + lr)*TBK + sw*8);
        #pragma unroll
        for (int mt = 0; mt < 4; ++mt)
            #pragma unroll
            for (int nt = 0; nt < 8; ++nt)
                acc[mt][nt] = __builtin_amdgcn_mfma_f32_16x16x32_bf16(a[mt], b[nt], acc[mt][nt], 0, 0, 0);
        __syncthreads();
    }
    float bv[8], w2v[8];
    #pragma unroll
    for (int nt = 0; nt < 8; ++nt) {
        int n = nb + nt*16 + lr;
        bv[nt] = bias[n];
        w2v[nt] = w2[n];
    }
    #pragma unroll
    for (int mt = 0; mt < 4; ++mt)
        #pragma unroll
        for (int r4 = 0; r4 < 4; ++r4) {
            int ml = mt*16 + q*4 + r4;
            float s = 0.f;
            #pragma unroll
            for (int nt = 0; nt < 8; ++nt)
                s += gelu_t(acc[mt][nt][r4] + bv[nt]) * w2v[nt];
            #pragma unroll
            for (int off = 8; off > 0; off >>= 1) s += __shfl_down(s, off, 16);
            if (lr == 0) red[wv*64 + ml] = s;
        }
    __syncthreads();
    if (tid < 128) {
        int msf = tid >> 6, ml = tid & 63;
        float t = red[(msf*4+0)*64 + ml] + red[(msf*4+1)*64 + ml]
                + red[(msf*4+2)*64 + ml] + red[(msf*4+3)*64 + ml];
        out[blockIdx.x*128 + tid] = t + b2[0];
    }
}

extern "C" void kernel_launch(void* const* d_in, const int* in_sizes, int n_in,
                              void* d_out, int out_size, void* d_ws, size_t ws_size,
                              hipStream_t stream) {
    const float* points = (const float*)d_in[0];
    const float* images = (const float*)d_in[1];
    const float* pw1 = (const float*)d_in[2];  const float* pb1 = (const float*)d_in[3];
    const float* pw2 = (const float*)d_in[4];  const float* pb2 = (const float*)d_in[5];
    const float* pw3 = (const float*)d_in[6];  const float* pb3 = (const float*)d_in[7];
    const float* gw1 = (const float*)d_in[8];  const float* gb1 = (const float*)d_in[9];
    const float* gw2 = (const float*)d_in[10]; const float* gb2 = (const float*)d_in[11];
    const float* gw3 = (const float*)d_in[12]; const float* gb3 = (const float*)d_in[13];
    const float* gw4 = (const float*)d_in[14]; const float* gb4 = (const float*)d_in[15];
    const float* gw5 = (const float*)d_in[16]; const float* gb5 = (const float*)d_in[17];
    const float* lw1 = (const float*)d_in[18]; const float* lb1 = (const float*)d_in[19];
    const float* lw2 = (const float*)d_in[20]; const float* lb2 = (const float*)d_in[21];
    const float* hw1 = (const float*)d_in[22]; const float* hb1 = (const float*)d_in[23];
    const float* hw2 = (const float*)d_in[24]; const float* hb2 = (const float*)d_in[25];
    float* out = (float*)d_out;

    // ---- workspace layout ----
    char* base = (char*)d_ws;
    unsigned short* fused_b = (unsigned short*)base;                       // M*576 bf16
    unsigned short* hid_b   = fused_b + (size_t)M_TOT*576;                 // (spacer)
    float4* fmap4 = (float4*)(hid_b + (size_t)M_TOT*256);                  // 16*3136 float4
    float* gc   = (float*)(fmap4 + (size_t)16*3136);                       // 1024
    unsigned short* blw1 = (unsigned short*)(gc + 1024);                   // 256*64
    unsigned short* blw2 = blw1 + 256*64;                                  // 256*256
    unsigned short* bhw1 = blw2 + 256*256;                                 // 512*576
    // conv temps alias inside the fused region (dead before mlp12 writes fused):
    float* ct = (float*)base;
    float* f1 = ct;
    float* f2 = f1 + (size_t)16*16*112*112;
    float* g1 = f2 + (size_t)16*32*56*56;
    float* g2 = g1 + (size_t)16*4*112*112;
    float* g3 = g2 + (size_t)16*8*56*56;
    float* g4 = g3 + (size_t)16*16*28*28;
    float* g5 = g4 + (size_t)16*32*14*14;

    cvtall_k<<<1472, 256, 0, stream>>>(lw1, lw2, hw1, blw1, blw2, bhw1);
    // conv1 of both encoders fused (shared image read)
    conv_dual_k<<<dim3(7,7,16), 256, 0, stream>>>(images, pw1, pb1, gw1, gb1, f1, g1);
    // plane encoder tail
    conv_tile_k<16,32,2><<<dim3(4,4,16), 256, 0, stream>>>(f1, pw2, pb2, f2, 112,112, 56,56);
    conv_p3_k<<<dim3(4,4,16), 256, 0, stream>>>(f2, pw3, pb3, fmap4);
    // global encoder tail
    conv_tile_k<4,8,2>  <<<dim3(4,4,16), 256, 0, stream>>>(g1, gw2, gb2, g2, 112,112, 56,56);
    conv_tile_k<8,16,2> <<<dim3(2,2,16), 256, 0, stream>>>(g2, gw3, gb3, g3,  56, 56, 28,28);
    conv3x3_k<<<dim3(2,2,16*32), dim3(8,8), 0, stream>>>(g3, gw4, gb4, g4, 16, 28, 28, 32, 14, 14, 2);
    conv3x3_k<<<dim3(1,1,16*64), dim3(8,8), 0, stream>>>(g4, gw5, gb5, g5, 32, 14, 14, 64,  7,  7, 2);
    avgpool7_k<<<4, 256, 0, stream>>>(g5, gc);
    // point branch: embed + mlp1 + mlp2 + patch/gc fill, all fused
    mlp12_k<<<M_TOT/128, 512, 0, stream>>>(points, blw1, lb1, blw2, lb2, fused_b, fmap4, gc);
    // head, M-strip 128
    gemm_hd_k<<<M_TOT/128, 512, 0, stream>>>(fused_b, 576, bhw1, 576, hb1, hw2, hb2, out, 576);
}